// Round 5
// baseline (67.640 us; speedup 1.0000x reference)
//
#include <hip/hip_runtime.h>
#include <math.h>

#define N_   16
#define L_   512
#define C_   256
#define T_   4096
#define EPSL 1e-5f
#define NBLK 512          // fused conv grid

typedef short short8 __attribute__((ext_vector_type(8)));
typedef float f32x4  __attribute__((ext_vector_type(4)));

__device__ __forceinline__ ushort f2bf(float f) {
    union { float f; unsigned u; } v; v.f = f;
    return (ushort)((v.u + 0x7FFF + ((v.u >> 16) & 1)) >> 16);
}

// ---------------------------------------------------------------------------
// pack BOTH conv weights into MFMA B-fragment order (bf16) + zero counter:
//   bpk[karm][cg(16)][s(8)][lane(64)][e(8)]
//   = w[karm][cin = s*32 + (lane>>4)*8 + e][cout = cg*16 + (lane&15)]
// ---------------------------------------------------------------------------
__global__ __launch_bounds__(256) void pack_w_kernel(
    const float* __restrict__ w1, const float* __restrict__ w2,
    ushort* __restrict__ bpk1, ushort* __restrict__ bpk2,
    int* __restrict__ counter)
{
    int gid = blockIdx.x * 256 + threadIdx.x;        // 49152 total
    if (gid == 0) *counter = 0;
    const float* w  = (gid < 24576) ? w1 : w2;
    ushort* bpk     = (gid < 24576) ? bpk1 : bpk2;
    int g2 = gid & 24575;
    int lane = g2 & 63;
    int s    = (g2 >> 6) & 7;
    int cg   = (g2 >> 9) & 15;
    int karm = g2 >> 13;
    int cin0 = s * 32 + (lane >> 4) * 8;
    int cout = cg * 16 + (lane & 15);
    const float* src = w + (size_t)(karm * 256 + cin0) * 256 + cout;
    short8 o;
    #pragma unroll
    for (int e = 0; e < 8; ++e) o[e] = (short)f2bf(src[(size_t)e * 256]);
    *reinterpret_cast<short8*>(bpk + (size_t)g2 * 8) = o;
}

// ---------------------------------------------------------------------------
// FUSED: conv1+bias+LN+ReLU (to LDS) -> conv2+bias+LN+ReLU+linear -> dur.
// Block = 512 thr (8 waves) owns 16 dur rows. conv1 computes the 18-row h1
// halo via two 16-row MFMA tiles (tile1: only 2 rows kept). Last block
// (atomic counter) performs the per-batch scans + WVF_pos tail.
// ---------------------------------------------------------------------------
__global__ __launch_bounds__(512) void fused_conv_kernel(
    const float* __restrict__ x,
    const ushort* __restrict__ bpk1, const ushort* __restrict__ bpk2,
    const float* __restrict__ b1, const float* __restrict__ g1, const float* __restrict__ be1,
    const float* __restrict__ b2, const float* __restrict__ g2, const float* __restrict__ be2,
    const float* __restrict__ lw, const float* __restrict__ lb,
    int* __restrict__ dur, int* __restrict__ ends, float* __restrict__ wpos,
    int* __restrict__ counter)
{
    __shared__ __align__(16) char xt[34 * 512];      // x tile (rows 20..33 unstaged junk, unused)
    __shared__ __align__(16) char h1t[18 * 512];     // h1 halo rows l0-1..l0+16, swizzled bf16
    __shared__ float redS[8][16], redQ[8][16], redP[8][16];
    __shared__ int lastFlag;

    const int tid  = threadIdx.x;
    const int wv   = tid >> 6;
    const int lane = tid & 63;
    const int lg   = lane >> 4;
    const int lr   = lane & 15;
    const int n    = blockIdx.x >> 5;
    const int l0   = (blockIdx.x & 31) << 4;
    const int cg0  = wv * 2;
    const int col0 = wv * 32 + lr, col1 = col0 + 16;

    // ---- stage x rows l0-2 .. l0+17 (20 rows), f32 -> bf16, XOR-swizzled ----
    for (int idx = tid; idx < 20 * 32; idx += 512) {
        int r = idx >> 5, slot = idx & 31;
        int l = l0 - 2 + r;
        short8 vb = {0,0,0,0,0,0,0,0};
        if (l >= 0 && l < L_) {
            const float* src = x + (((size_t)(n * L_ + l)) << 8) + (slot << 3);
            f32x4 f0 = *reinterpret_cast<const f32x4*>(src);
            f32x4 f1 = *reinterpret_cast<const f32x4*>(src + 4);
            vb[0]=(short)f2bf(f0[0]); vb[1]=(short)f2bf(f0[1]);
            vb[2]=(short)f2bf(f0[2]); vb[3]=(short)f2bf(f0[3]);
            vb[4]=(short)f2bf(f1[0]); vb[5]=(short)f2bf(f1[1]);
            vb[6]=(short)f2bf(f1[2]); vb[7]=(short)f2bf(f1[3]);
        }
        *reinterpret_cast<short8*>(xt + r * 512 + ((slot ^ (r & 15)) << 4)) = vb;
    }
    __syncthreads();

    // ---- conv1 MFMA: two row-tiles (rows l0-1.., l0+15..), B-frags shared ----
    f32x4 acc[2][2] = {};
    #pragma unroll
    for (int karm = 0; karm < 3; ++karm) {
        const ushort* bb = bpk1 + ((size_t)(karm * 16 + cg0)) * 4096 + lane * 8;
        #pragma unroll
        for (int s = 0; s < 8; ++s) {
            short8 bf0 = *reinterpret_cast<const short8*>(bb + s * 512);
            short8 bf1 = *reinterpret_cast<const short8*>(bb + 4096 + s * 512);
            #pragma unroll
            for (int t = 0; t < 2; ++t) {
                int rA = 16 * t + lr + karm;
                short8 a = *reinterpret_cast<const short8*>(
                    xt + rA * 512 + ((((s << 2) + lg) ^ (rA & 15)) << 4));
                acc[t][0] = __builtin_amdgcn_mfma_f32_16x16x32_bf16(a, bf0, acc[t][0], 0,0,0);
                acc[t][1] = __builtin_amdgcn_mfma_f32_16x16x32_bf16(a, bf1, acc[t][1], 0,0,0);
            }
        }
    }

    // ---- conv1 epilogue per tile: bias + LN + ReLU -> h1t (bf16, swizzled) ----
    const float bb0 = b1[col0], bb1 = b1[col1];
    const float gg0 = g1[col0], gg1 = g1[col1];
    const float ee0 = be1[col0], ee1 = be1[col1];

    #pragma unroll
    for (int t = 0; t < 2; ++t) {
        f32x4 s, q;
        float v0[4], v1[4];
        #pragma unroll
        for (int j = 0; j < 4; ++j) {
            float h0 = acc[t][0][j] + bb0, h1v = acc[t][1][j] + bb1;
            v0[j] = h0; v1[j] = h1v;
            s[j] = h0 + h1v; q[j] = h0 * h0 + h1v * h1v;
        }
        #pragma unroll
        for (int m = 1; m < 16; m <<= 1) {
            #pragma unroll
            for (int j = 0; j < 4; ++j) {
                s[j] += __shfl_xor(s[j], m, 64);
                q[j] += __shfl_xor(q[j], m, 64);
            }
        }
        if (lr == 0) {
            #pragma unroll
            for (int j = 0; j < 4; ++j) { redS[wv][lg*4+j] = s[j]; redQ[wv][lg*4+j] = q[j]; }
        }
        __syncthreads();
        #pragma unroll
        for (int j = 0; j < 4; ++j) {
            int hr = 16 * t + lg * 4 + j;               // h1t row index
            if (hr < 18) {
                int hl = l0 - 1 + hr;                   // global h1 row
                float ss = 0.f, qq = 0.f;
                #pragma unroll
                for (int u = 0; u < 8; ++u) { ss += redS[u][lg*4+j]; qq += redQ[u][lg*4+j]; }
                float m_  = ss * (1.f / 256.f);
                float var = fmaxf(qq * (1.f / 256.f) - m_ * m_, 0.f);
                float rstd = 1.0f / sqrtf(var + EPSL);
                float r0 = 0.f, r1 = 0.f;
                if (hl >= 0 && hl < L_) {               // conv2 'same' zero padding
                    r0 = fmaxf((v0[j] - m_) * rstd * gg0 + ee0, 0.f);
                    r1 = fmaxf((v1[j] - m_) * rstd * gg1 + ee1, 0.f);
                }
                *(ushort*)(h1t + hr*512 + (((col0 >> 3) ^ (hr & 15)) << 4) + (col0 & 7) * 2) = f2bf(r0);
                *(ushort*)(h1t + hr*512 + (((col1 >> 3) ^ (hr & 15)) << 4) + (col1 & 7) * 2) = f2bf(r1);
            }
        }
        __syncthreads();
    }

    // ---- conv2 MFMA (reads h1t) ----
    f32x4 c2[2] = {};
    #pragma unroll
    for (int karm = 0; karm < 3; ++karm) {
        const ushort* bb = bpk2 + ((size_t)(karm * 16 + cg0)) * 4096 + lane * 8;
        const int rA = lr + karm;
        const char* abase = h1t + rA * 512;
        const int rx = rA & 15;
        #pragma unroll
        for (int s = 0; s < 8; ++s) {
            short8 a = *reinterpret_cast<const short8*>(abase + ((((s << 2) + lg) ^ rx) << 4));
            short8 bf0 = *reinterpret_cast<const short8*>(bb + s * 512);
            short8 bf1 = *reinterpret_cast<const short8*>(bb + 4096 + s * 512);
            c2[0] = __builtin_amdgcn_mfma_f32_16x16x32_bf16(a, bf0, c2[0], 0,0,0);
            c2[1] = __builtin_amdgcn_mfma_f32_16x16x32_bf16(a, bf1, c2[1], 0,0,0);
        }
    }

    // ---- conv2 epilogue: bias + LN + ReLU + dot(lw) -> dur ----
    const float cb0 = b2[col0], cb1 = b2[col1];
    const float wg0 = g2[col0], wg1 = g2[col1];
    const float we0 = be2[col0], we1 = be2[col1];
    const float lw0 = lw[col0],  lw1 = lw[col1];

    {
        f32x4 s, q;
        float u0[4], u1[4];
        #pragma unroll
        for (int j = 0; j < 4; ++j) {
            float h0 = c2[0][j] + cb0, h1v = c2[1][j] + cb1;
            u0[j] = h0; u1[j] = h1v;
            s[j] = h0 + h1v; q[j] = h0 * h0 + h1v * h1v;
        }
        #pragma unroll
        for (int m = 1; m < 16; m <<= 1) {
            #pragma unroll
            for (int j = 0; j < 4; ++j) {
                s[j] += __shfl_xor(s[j], m, 64);
                q[j] += __shfl_xor(q[j], m, 64);
            }
        }
        if (lr == 0) {
            #pragma unroll
            for (int j = 0; j < 4; ++j) { redS[wv][lg*4+j] = s[j]; redQ[wv][lg*4+j] = q[j]; }
        }
        __syncthreads();
        f32x4 p;
        #pragma unroll
        for (int j = 0; j < 4; ++j) {
            float ss = 0.f, qq = 0.f;
            #pragma unroll
            for (int u = 0; u < 8; ++u) { ss += redS[u][lg*4+j]; qq += redQ[u][lg*4+j]; }
            float m_  = ss * (1.f / 256.f);
            float var = fmaxf(qq * (1.f / 256.f) - m_ * m_, 0.f);
            float rstd = 1.0f / sqrtf(var + EPSL);
            float r0 = fmaxf((u0[j] - m_) * rstd * wg0 + we0, 0.f);
            float r1 = fmaxf((u1[j] - m_) * rstd * wg1 + we1, 0.f);
            p[j] = r0 * lw0 + r1 * lw1;
        }
        #pragma unroll
        for (int m = 1; m < 16; m <<= 1) {
            #pragma unroll
            for (int j = 0; j < 4; ++j) p[j] += __shfl_xor(p[j], m, 64);
        }
        if (lr == 0) {
            #pragma unroll
            for (int j = 0; j < 4; ++j) redP[wv][lg*4+j] = p[j];
        }
        __syncthreads();
        if (tid < 16) {
            float dot = lb[0];
            #pragma unroll
            for (int u = 0; u < 8; ++u) dot += redP[u][tid];
            dur[n * L_ + l0 + tid] = (int)(fmaxf(dot, 0.f) + 0.5f);
        }
    }

    // ---- last block: scan durations per batch + WVF_pos ----
    __syncthreads();
    if (tid == 0) {
        __threadfence();
        int old = __hip_atomic_fetch_add(counter, 1, __ATOMIC_ACQ_REL, __HIP_MEMORY_SCOPE_AGENT);
        lastFlag = (old == NBLK - 1) ? 1 : 0;
    }
    __syncthreads();
    if (!lastFlag) return;
    __threadfence();

    #pragma unroll
    for (int k = 0; k < 8; ++k)
        wpos[k * 512 + tid] = (float)(k * 512 + tid + 1);

    #pragma unroll
    for (int pass = 0; pass < 2; ++pass) {
        int nn = pass * 8 + wv;                        // wave per batch row
        const int* dsrc = dur + nn * L_;
        int4 va = reinterpret_cast<const int4*>(dsrc)[lane * 2];
        int4 vb = reinterpret_cast<const int4*>(dsrc)[lane * 2 + 1];
        int p0 = va.x,      p1 = p0 + va.y, p2 = p1 + va.z, p3 = p2 + va.w;
        int p4 = p3 + vb.x, p5 = p4 + vb.y, p6 = p5 + vb.z, p7 = p6 + vb.w;
        int tot = p7;
        #pragma unroll
        for (int m = 1; m < 64; m <<= 1) {
            int tu = __shfl_up(tot, m, 64);
            if (lane >= m) tot += tu;
        }
        int off = tot - p7;                            // exclusive prefix of lane totals
        int* edst = ends + nn * L_;
        int4 o1 = make_int4(p0 + off, p1 + off, p2 + off, p3 + off);
        int4 o2 = make_int4(p4 + off, p5 + off, p6 + off, p7 + off);
        reinterpret_cast<int4*>(edst)[lane * 2]     = o1;
        reinterpret_cast<int4*>(edst)[lane * 2 + 1] = o2;
    }
}

// ---------------------------------------------------------------------------
// gather: wave-per-output-row; binary search over ends; nontemporal stores
// ---------------------------------------------------------------------------
__global__ __launch_bounds__(512) void gather_kernel(
    const float* __restrict__ x, const int* __restrict__ ends,
    float* __restrict__ out)
{
    const int wid = threadIdx.x >> 6, lane = threadIdx.x & 63;
    const int row = blockIdx.x * 8 + wid;   // row = n*T + t
    const int n = row >> 12;
    const int t = row & (T_ - 1);
    const int* e = ends + n * L_;
    const int total = e[L_ - 1];

    f32x4 v = {0.f, 0.f, 0.f, 0.f};
    if (t < total) {
        int p = 0;
        #pragma unroll
        for (int step = 256; step > 0; step >>= 1)
            if (p + step <= L_ && e[p + step - 1] <= t) p += step;
        v = reinterpret_cast<const f32x4*>(x + (((size_t)(n * L_ + p)) << 8))[lane];
    }
    __builtin_nontemporal_store(v, reinterpret_cast<f32x4*>(out + ((size_t)row << 8)) + lane);
}

// ---------------------------------------------------------------------------
extern "C" void kernel_launch(void* const* d_in, const int* in_sizes, int n_in,
                              void* d_out, int out_size, void* d_ws, size_t ws_size,
                              hipStream_t stream)
{
    const float* x   = (const float*)d_in[0];
    const float* w1  = (const float*)d_in[1];
    const float* b1  = (const float*)d_in[2];
    const float* g1  = (const float*)d_in[3];
    const float* be1 = (const float*)d_in[4];
    const float* w2  = (const float*)d_in[5];
    const float* b2  = (const float*)d_in[6];
    const float* g2  = (const float*)d_in[7];
    const float* be2 = (const float*)d_in[8];
    const float* lw  = (const float*)d_in[9];
    const float* lb  = (const float*)d_in[10];

    float* out = (float*)d_out;
    // weight-fragment scratch in d_out head (first 768 KB; gather overwrites)
    ushort* bpk1 = (ushort*)d_out;
    ushort* bpk2 = bpk1 + 196608;
    int* dur     = (int*)d_ws;
    int* ends    = dur + N_ * L_;
    int* counter = ends + N_ * L_;

    pack_w_kernel<<<192, 256, 0, stream>>>(w1, w2, bpk1, bpk2, counter);

    fused_conv_kernel<<<NBLK, 512, 0, stream>>>(
        x, bpk1, bpk2, b1, g1, be1, b2, g2, be2, lw, lb,
        dur, ends, out + (size_t)N_ * T_ * C_, counter);

    gather_kernel<<<N_ * T_ / 8, 512, 0, stream>>>(x, ends, out);
}

// Round 6
// 52.917 us; speedup vs baseline: 1.2782x; 1.2782x over previous
//
#include <hip/hip_runtime.h>
#include <math.h>

#define N_   16
#define L_   512
#define C_   256
#define T_   4096
#define EPSL 1e-5f
#define NBLK 512          // fused conv grid

typedef short short8 __attribute__((ext_vector_type(8)));
typedef float f32x4  __attribute__((ext_vector_type(4)));

__device__ __forceinline__ ushort f2bf(float f) {
    union { float f; unsigned u; } v; v.f = f;
    return (ushort)((v.u + 0x7FFF + ((v.u >> 16) & 1)) >> 16);
}

// ---------------------------------------------------------------------------
// pack BOTH conv weights into MFMA B-fragment order (bf16):
//   bpk[karm][cg(16)][s(8)][lane(64)][e(8)]
//   = w[karm][cin = s*32 + (lane>>4)*8 + e][cout = cg*16 + (lane&15)]
// ---------------------------------------------------------------------------
__global__ __launch_bounds__(256) void pack_w_kernel(
    const float* __restrict__ w1, const float* __restrict__ w2,
    ushort* __restrict__ bpk1, ushort* __restrict__ bpk2)
{
    int gid = blockIdx.x * 256 + threadIdx.x;        // 49152 total
    const float* w  = (gid < 24576) ? w1 : w2;
    ushort* bpk     = (gid < 24576) ? bpk1 : bpk2;
    int g2 = gid & 24575;
    int lane = g2 & 63;
    int s    = (g2 >> 6) & 7;
    int cg   = (g2 >> 9) & 15;
    int karm = g2 >> 13;
    int cin0 = s * 32 + (lane >> 4) * 8;
    int cout = cg * 16 + (lane & 15);
    const float* src = w + (size_t)(karm * 256 + cin0) * 256 + cout;
    short8 o;
    #pragma unroll
    for (int e = 0; e < 8; ++e) o[e] = (short)f2bf(src[(size_t)e * 256]);
    *reinterpret_cast<short8*>(bpk + (size_t)g2 * 8) = o;
}

// ---------------------------------------------------------------------------
// FUSED: conv1+bias+LN+ReLU (h1 -> LDS only) -> conv2+bias+LN+ReLU+linear
// -> dur. Block = 512 thr (8 waves) owns 16 dur rows. conv1 computes the
// 18-row h1 halo via two 16-row MFMA tiles (tile1: only 2 rows kept).
// NO cross-block sync/fence — scan runs as a separate tiny kernel.
// ---------------------------------------------------------------------------
__global__ __launch_bounds__(512) void fused_conv_kernel(
    const float* __restrict__ x,
    const ushort* __restrict__ bpk1, const ushort* __restrict__ bpk2,
    const float* __restrict__ b1, const float* __restrict__ g1, const float* __restrict__ be1,
    const float* __restrict__ b2, const float* __restrict__ g2, const float* __restrict__ be2,
    const float* __restrict__ lw, const float* __restrict__ lb,
    int* __restrict__ dur)
{
    __shared__ __align__(16) char xt[20 * 512];      // x rows l0-2 .. l0+17, swizzled bf16
    __shared__ __align__(16) char h1t[18 * 512];     // h1 rows l0-1 .. l0+16, swizzled bf16
    __shared__ float redS[8][16], redQ[8][16], redP[8][16];

    const int tid  = threadIdx.x;
    const int wv   = tid >> 6;
    const int lane = tid & 63;
    const int lg   = lane >> 4;
    const int lr   = lane & 15;
    const int n    = blockIdx.x >> 5;
    const int l0   = (blockIdx.x & 31) << 4;
    const int cg0  = wv * 2;
    const int col0 = wv * 32 + lr, col1 = col0 + 16;

    // ---- stage x rows l0-2 .. l0+17 (20 rows), f32 -> bf16, XOR-swizzled ----
    for (int idx = tid; idx < 20 * 32; idx += 512) {
        int r = idx >> 5, slot = idx & 31;
        int l = l0 - 2 + r;
        short8 vb = {0,0,0,0,0,0,0,0};
        if (l >= 0 && l < L_) {
            const float* src = x + (((size_t)(n * L_ + l)) << 8) + (slot << 3);
            f32x4 f0 = *reinterpret_cast<const f32x4*>(src);
            f32x4 f1 = *reinterpret_cast<const f32x4*>(src + 4);
            vb[0]=(short)f2bf(f0[0]); vb[1]=(short)f2bf(f0[1]);
            vb[2]=(short)f2bf(f0[2]); vb[3]=(short)f2bf(f0[3]);
            vb[4]=(short)f2bf(f1[0]); vb[5]=(short)f2bf(f1[1]);
            vb[6]=(short)f2bf(f1[2]); vb[7]=(short)f2bf(f1[3]);
        }
        *reinterpret_cast<short8*>(xt + r * 512 + ((slot ^ (r & 15)) << 4)) = vb;
    }
    __syncthreads();

    // ---- conv1 MFMA: two row-tiles (rows l0-1.., l0+15..), B-frags shared ----
    f32x4 acc[2][2] = {};
    #pragma unroll
    for (int karm = 0; karm < 3; ++karm) {
        const ushort* bb = bpk1 + ((size_t)(karm * 16 + cg0)) * 4096 + lane * 8;
        #pragma unroll
        for (int s = 0; s < 8; ++s) {
            short8 bf0 = *reinterpret_cast<const short8*>(bb + s * 512);
            short8 bf1 = *reinterpret_cast<const short8*>(bb + 4096 + s * 512);
            #pragma unroll
            for (int t = 0; t < 2; ++t) {
                int rA = 16 * t + lr + karm;
                short8 a = *reinterpret_cast<const short8*>(
                    xt + rA * 512 + ((((s << 2) + lg) ^ (rA & 15)) << 4));
                acc[t][0] = __builtin_amdgcn_mfma_f32_16x16x32_bf16(a, bf0, acc[t][0], 0,0,0);
                acc[t][1] = __builtin_amdgcn_mfma_f32_16x16x32_bf16(a, bf1, acc[t][1], 0,0,0);
            }
        }
    }

    // ---- conv1 epilogue per tile: bias + LN + ReLU -> h1t (bf16, swizzled) ----
    const float bb0 = b1[col0], bb1 = b1[col1];
    const float gg0 = g1[col0], gg1 = g1[col1];
    const float ee0 = be1[col0], ee1 = be1[col1];

    #pragma unroll
    for (int t = 0; t < 2; ++t) {
        f32x4 s, q;
        float v0[4], v1[4];
        #pragma unroll
        for (int j = 0; j < 4; ++j) {
            float h0 = acc[t][0][j] + bb0, h1v = acc[t][1][j] + bb1;
            v0[j] = h0; v1[j] = h1v;
            s[j] = h0 + h1v; q[j] = h0 * h0 + h1v * h1v;
        }
        #pragma unroll
        for (int m = 1; m < 16; m <<= 1) {
            #pragma unroll
            for (int j = 0; j < 4; ++j) {
                s[j] += __shfl_xor(s[j], m, 64);
                q[j] += __shfl_xor(q[j], m, 64);
            }
        }
        if (lr == 0) {
            #pragma unroll
            for (int j = 0; j < 4; ++j) { redS[wv][lg*4+j] = s[j]; redQ[wv][lg*4+j] = q[j]; }
        }
        __syncthreads();
        #pragma unroll
        for (int j = 0; j < 4; ++j) {
            int hr = 16 * t + lg * 4 + j;               // h1t row index
            if (hr < 18) {
                int hl = l0 - 1 + hr;                   // global h1 row
                float ss = 0.f, qq = 0.f;
                #pragma unroll
                for (int u = 0; u < 8; ++u) { ss += redS[u][lg*4+j]; qq += redQ[u][lg*4+j]; }
                float m_  = ss * (1.f / 256.f);
                float var = fmaxf(qq * (1.f / 256.f) - m_ * m_, 0.f);
                float rstd = 1.0f / sqrtf(var + EPSL);
                float r0 = 0.f, r1 = 0.f;
                if (hl >= 0 && hl < L_) {               // conv2 'same' zero padding
                    r0 = fmaxf((v0[j] - m_) * rstd * gg0 + ee0, 0.f);
                    r1 = fmaxf((v1[j] - m_) * rstd * gg1 + ee1, 0.f);
                }
                *(ushort*)(h1t + hr*512 + (((col0 >> 3) ^ (hr & 15)) << 4) + (col0 & 7) * 2) = f2bf(r0);
                *(ushort*)(h1t + hr*512 + (((col1 >> 3) ^ (hr & 15)) << 4) + (col1 & 7) * 2) = f2bf(r1);
            }
        }
        __syncthreads();
    }

    // ---- conv2 MFMA (reads h1t) ----
    f32x4 c2[2] = {};
    #pragma unroll
    for (int karm = 0; karm < 3; ++karm) {
        const ushort* bb = bpk2 + ((size_t)(karm * 16 + cg0)) * 4096 + lane * 8;
        const int rA = lr + karm;
        const char* abase = h1t + rA * 512;
        const int rx = rA & 15;
        #pragma unroll
        for (int s = 0; s < 8; ++s) {
            short8 a = *reinterpret_cast<const short8*>(abase + ((((s << 2) + lg) ^ rx) << 4));
            short8 bf0 = *reinterpret_cast<const short8*>(bb + s * 512);
            short8 bf1 = *reinterpret_cast<const short8*>(bb + 4096 + s * 512);
            c2[0] = __builtin_amdgcn_mfma_f32_16x16x32_bf16(a, bf0, c2[0], 0,0,0);
            c2[1] = __builtin_amdgcn_mfma_f32_16x16x32_bf16(a, bf1, c2[1], 0,0,0);
        }
    }

    // ---- conv2 epilogue: bias + LN + ReLU + dot(lw) -> dur ----
    const float cb0 = b2[col0], cb1 = b2[col1];
    const float wg0 = g2[col0], wg1 = g2[col1];
    const float we0 = be2[col0], we1 = be2[col1];
    const float lw0 = lw[col0],  lw1 = lw[col1];

    f32x4 s, q;
    float u0[4], u1[4];
    #pragma unroll
    for (int j = 0; j < 4; ++j) {
        float h0 = c2[0][j] + cb0, h1v = c2[1][j] + cb1;
        u0[j] = h0; u1[j] = h1v;
        s[j] = h0 + h1v; q[j] = h0 * h0 + h1v * h1v;
    }
    #pragma unroll
    for (int m = 1; m < 16; m <<= 1) {
        #pragma unroll
        for (int j = 0; j < 4; ++j) {
            s[j] += __shfl_xor(s[j], m, 64);
            q[j] += __shfl_xor(q[j], m, 64);
        }
    }
    if (lr == 0) {
        #pragma unroll
        for (int j = 0; j < 4; ++j) { redS[wv][lg*4+j] = s[j]; redQ[wv][lg*4+j] = q[j]; }
    }
    __syncthreads();
    f32x4 p;
    #pragma unroll
    for (int j = 0; j < 4; ++j) {
        float ss = 0.f, qq = 0.f;
        #pragma unroll
        for (int u = 0; u < 8; ++u) { ss += redS[u][lg*4+j]; qq += redQ[u][lg*4+j]; }
        float m_  = ss * (1.f / 256.f);
        float var = fmaxf(qq * (1.f / 256.f) - m_ * m_, 0.f);
        float rstd = 1.0f / sqrtf(var + EPSL);
        float r0 = fmaxf((u0[j] - m_) * rstd * wg0 + we0, 0.f);
        float r1 = fmaxf((u1[j] - m_) * rstd * wg1 + we1, 0.f);
        p[j] = r0 * lw0 + r1 * lw1;
    }
    #pragma unroll
    for (int m = 1; m < 16; m <<= 1) {
        #pragma unroll
        for (int j = 0; j < 4; ++j) p[j] += __shfl_xor(p[j], m, 64);
    }
    if (lr == 0) {
        #pragma unroll
        for (int j = 0; j < 4; ++j) redP[wv][lg*4+j] = p[j];
    }
    __syncthreads();
    if (tid < 16) {
        float dot = lb[0];
        #pragma unroll
        for (int u = 0; u < 8; ++u) dot += redP[u][tid];
        dur[n * L_ + l0 + tid] = (int)(fmaxf(dot, 0.f) + 0.5f);
    }
}

// ---------------------------------------------------------------------------
// per-batch inclusive scan (one wave per batch row) + WVF_pos tail
// ---------------------------------------------------------------------------
__global__ __launch_bounds__(64) void scan_pos_kernel(
    const int* __restrict__ dur, int* __restrict__ ends, float* __restrict__ wpos)
{
    const int n = blockIdx.x, lane = threadIdx.x;
    #pragma unroll
    for (int k = 0; k < 4; ++k) {
        int i = n * 256 + k * 64 + lane;
        wpos[i] = (float)(i + 1);
    }
    const int* dsrc = dur + n * L_;
    int4 va = reinterpret_cast<const int4*>(dsrc)[lane * 2];
    int4 vb = reinterpret_cast<const int4*>(dsrc)[lane * 2 + 1];
    int p0 = va.x,      p1 = p0 + va.y, p2 = p1 + va.z, p3 = p2 + va.w;
    int p4 = p3 + vb.x, p5 = p4 + vb.y, p6 = p5 + vb.z, p7 = p6 + vb.w;
    int tot = p7;
    #pragma unroll
    for (int m = 1; m < 64; m <<= 1) {
        int tu = __shfl_up(tot, m, 64);
        if (lane >= m) tot += tu;
    }
    int off = tot - p7;                            // exclusive prefix of lane totals
    int* edst = ends + n * L_;
    int4 o1 = make_int4(p0 + off, p1 + off, p2 + off, p3 + off);
    int4 o2 = make_int4(p4 + off, p5 + off, p6 + off, p7 + off);
    reinterpret_cast<int4*>(edst)[lane * 2]     = o1;
    reinterpret_cast<int4*>(edst)[lane * 2 + 1] = o2;
}

// ---------------------------------------------------------------------------
// gather: wave-per-output-row; binary search over ends; nontemporal stores
// ---------------------------------------------------------------------------
__global__ __launch_bounds__(512) void gather_kernel(
    const float* __restrict__ x, const int* __restrict__ ends,
    float* __restrict__ out)
{
    const int wid = threadIdx.x >> 6, lane = threadIdx.x & 63;
    const int row = blockIdx.x * 8 + wid;   // row = n*T + t
    const int n = row >> 12;
    const int t = row & (T_ - 1);
    const int* e = ends + n * L_;
    const int total = e[L_ - 1];

    f32x4 v = {0.f, 0.f, 0.f, 0.f};
    if (t < total) {
        int p = 0;
        #pragma unroll
        for (int step = 256; step > 0; step >>= 1)
            if (p + step <= L_ && e[p + step - 1] <= t) p += step;
        v = reinterpret_cast<const f32x4*>(x + (((size_t)(n * L_ + p)) << 8))[lane];
    }
    __builtin_nontemporal_store(v, reinterpret_cast<f32x4*>(out + ((size_t)row << 8)) + lane);
}

// ---------------------------------------------------------------------------
extern "C" void kernel_launch(void* const* d_in, const int* in_sizes, int n_in,
                              void* d_out, int out_size, void* d_ws, size_t ws_size,
                              hipStream_t stream)
{
    const float* x   = (const float*)d_in[0];
    const float* w1  = (const float*)d_in[1];
    const float* b1  = (const float*)d_in[2];
    const float* g1  = (const float*)d_in[3];
    const float* be1 = (const float*)d_in[4];
    const float* w2  = (const float*)d_in[5];
    const float* b2  = (const float*)d_in[6];
    const float* g2  = (const float*)d_in[7];
    const float* be2 = (const float*)d_in[8];
    const float* lw  = (const float*)d_in[9];
    const float* lb  = (const float*)d_in[10];

    float* out = (float*)d_out;
    // weight-fragment scratch in d_out head (first 768 KB; gather overwrites)
    ushort* bpk1 = (ushort*)d_out;
    ushort* bpk2 = bpk1 + 196608;
    int* dur     = (int*)d_ws;
    int* ends    = dur + N_ * L_;

    pack_w_kernel<<<192, 256, 0, stream>>>(w1, w2, bpk1, bpk2);

    fused_conv_kernel<<<NBLK, 512, 0, stream>>>(
        x, bpk1, bpk2, b1, g1, be1, b2, g2, be2, lw, lb, dur);

    scan_pos_kernel<<<N_, 64, 0, stream>>>(dur, ends, out + (size_t)N_ * T_ * C_);

    gather_kernel<<<N_ * T_ / 8, 512, 0, stream>>>(x, ends, out);
}

// Round 7
// 42.027 us; speedup vs baseline: 1.6094x; 1.2591x over previous
//
#include <hip/hip_runtime.h>
#include <math.h>

#define N_   16
#define L_   512
#define C_   256
#define T_   4096
#define EPSL 1e-5f
#define BM   32           // dur rows per block

typedef short short8 __attribute__((ext_vector_type(8)));
typedef float f32x4  __attribute__((ext_vector_type(4)));

__device__ __forceinline__ ushort f2bf(float f) {
    union { float f; unsigned u; } v; v.f = f;
    return (ushort)((v.u + 0x7FFF + ((v.u >> 16) & 1)) >> 16);
}

// ---------------------------------------------------------------------------
// pack BOTH conv weights into MFMA B-fragment order (bf16):
//   bpk[karm][cg(16)][s(8)][lane(64)][e(8)]
//   = w[karm][cin = s*32 + (lane>>4)*8 + e][cout = cg*16 + (lane&15)]
// ---------------------------------------------------------------------------
__global__ __launch_bounds__(256) void pack_w_kernel(
    const float* __restrict__ w1, const float* __restrict__ w2,
    ushort* __restrict__ bpk1, ushort* __restrict__ bpk2)
{
    int gid = blockIdx.x * 256 + threadIdx.x;        // 49152 total
    const float* w  = (gid < 24576) ? w1 : w2;
    ushort* bpk     = (gid < 24576) ? bpk1 : bpk2;
    int g2 = gid & 24575;
    int lane = g2 & 63;
    int s    = (g2 >> 6) & 7;
    int cg   = (g2 >> 9) & 15;
    int karm = g2 >> 13;
    int cin0 = s * 32 + (lane >> 4) * 8;
    int cout = cg * 16 + (lane & 15);
    const float* src = w + (size_t)(karm * 256 + cin0) * 256 + cout;
    short8 o;
    #pragma unroll
    for (int e = 0; e < 8; ++e) o[e] = (short)f2bf(src[(size_t)e * 256]);
    *reinterpret_cast<short8*>(bpk + (size_t)g2 * 8) = o;
}

// ---------------------------------------------------------------------------
// FUSED conv1+LN+ReLU -> conv2+LN+ReLU+linear -> dur.
// Block = 1024 thr (16 waves) owns BM=32 dur rows; wave wv owns col-group wv
// (16 cols) across ALL row-tiles (conv1: 3 tiles of 16 rows covering the
// 34-row h1 halo; conv2: 2 tiles). B-frags batched 8-deep into registers.
// ---------------------------------------------------------------------------
__global__ __launch_bounds__(1024) void fused_conv_kernel(
    const float* __restrict__ x,
    const ushort* __restrict__ bpk1, const ushort* __restrict__ bpk2,
    const float* __restrict__ b1, const float* __restrict__ g1, const float* __restrict__ be1,
    const float* __restrict__ b2, const float* __restrict__ g2, const float* __restrict__ be2,
    const float* __restrict__ lw, const float* __restrict__ lb,
    int* __restrict__ dur)
{
    // xt oversized to 50 rows: conv1 tile-2 A-reads touch rows up to 49;
    // those C rows are discarded (C row r uses only lane-r's A data).
    __shared__ __align__(16) char xt[50 * 512];      // x rows l0-2.. staged 36, junk above
    __shared__ __align__(16) char h1t[34 * 512];     // h1 rows l0-1 .. l0+32
    __shared__ float redS[16][48], redQ[16][48], redP[16][32];

    const int tid  = threadIdx.x;
    const int wv   = tid >> 6;                       // 0..15 = col-group
    const int lane = tid & 63;
    const int lg   = lane >> 4;
    const int lr   = lane & 15;
    const int n    = blockIdx.x >> 4;
    const int l0   = (blockIdx.x & 15) << 5;
    const int col  = wv * 16 + lr;

    // ---- stage x rows l0-2 .. l0+33 (36 rows), f32 -> bf16, XOR-swizzled ----
    for (int idx = tid; idx < 36 * 32; idx += 1024) {
        int r = idx >> 5, slot = idx & 31;
        int l = l0 - 2 + r;
        short8 vb = {0,0,0,0,0,0,0,0};
        if (l >= 0 && l < L_) {
            const float* src = x + (((size_t)(n * L_ + l)) << 8) + (slot << 3);
            f32x4 f0 = *reinterpret_cast<const f32x4*>(src);
            f32x4 f1 = *reinterpret_cast<const f32x4*>(src + 4);
            vb[0]=(short)f2bf(f0[0]); vb[1]=(short)f2bf(f0[1]);
            vb[2]=(short)f2bf(f0[2]); vb[3]=(short)f2bf(f0[3]);
            vb[4]=(short)f2bf(f1[0]); vb[5]=(short)f2bf(f1[1]);
            vb[6]=(short)f2bf(f1[2]); vb[7]=(short)f2bf(f1[3]);
        }
        *reinterpret_cast<short8*>(xt + r * 512 + ((slot ^ (r & 15)) << 4)) = vb;
    }
    __syncthreads();

    // ---- conv1 MFMA: 3 row-tiles, B-frags batched 8-deep ----
    f32x4 a1[3] = {};
    #pragma unroll
    for (int karm = 0; karm < 3; ++karm) {
        const ushort* bb = bpk1 + ((size_t)(karm * 16 + wv)) * 4096 + lane * 8;
        short8 bfr[8];
        #pragma unroll
        for (int s = 0; s < 8; ++s)
            bfr[s] = *reinterpret_cast<const short8*>(bb + s * 512);
        #pragma unroll
        for (int s = 0; s < 8; ++s) {
            #pragma unroll
            for (int t = 0; t < 3; ++t) {
                int rA = 16 * t + lr + karm;
                short8 a = *reinterpret_cast<const short8*>(
                    xt + rA * 512 + ((((s << 2) + lg) ^ (rA & 15)) << 4));
                a1[t] = __builtin_amdgcn_mfma_f32_16x16x32_bf16(a, bfr[s], a1[t], 0, 0, 0);
            }
        }
    }

    // ---- conv1 stats: shfl over 16 cols, LDS combine over 16 waves ----
    const float cb1 = b1[col], cg1 = g1[col], ce1 = be1[col];
    {
        float sv[12], qv[12];
        #pragma unroll
        for (int t = 0; t < 3; ++t)
            #pragma unroll
            for (int j = 0; j < 4; ++j) {
                float h = a1[t][j] + cb1;
                sv[t*4+j] = h; qv[t*4+j] = h * h;
            }
        #pragma unroll
        for (int m = 1; m < 16; m <<= 1)
            #pragma unroll
            for (int k = 0; k < 12; ++k) {
                sv[k] += __shfl_xor(sv[k], m, 64);
                qv[k] += __shfl_xor(qv[k], m, 64);
            }
        if (lr == 0) {
            #pragma unroll
            for (int t = 0; t < 3; ++t)
                #pragma unroll
                for (int j = 0; j < 4; ++j) {
                    redS[wv][16*t + lg*4 + j] = sv[t*4+j];
                    redQ[wv][16*t + lg*4 + j] = qv[t*4+j];
                }
        }
    }
    __syncthreads();
    if (tid < 48) {                                  // reduce across waves
        float ss = 0.f, qq = 0.f;
        #pragma unroll
        for (int u = 0; u < 16; ++u) { ss += redS[u][tid]; qq += redQ[u][tid]; }
        float m_  = ss * (1.f / 256.f);
        float var = fmaxf(qq * (1.f / 256.f) - m_ * m_, 0.f);
        redS[0][tid] = m_;
        redQ[0][tid] = 1.0f / sqrtf(var + EPSL);
    }
    __syncthreads();

    // ---- normalize + ReLU -> h1t (rows 0..33 kept) ----
    #pragma unroll
    for (int t = 0; t < 3; ++t)
        #pragma unroll
        for (int j = 0; j < 4; ++j) {
            int hr = 16*t + lg*4 + j;
            if (hr < 34) {
                int hl = l0 - 1 + hr;
                float r = 0.f;
                if (hl >= 0 && hl < L_)
                    r = fmaxf((a1[t][j] + cb1 - redS[0][hr]) * redQ[0][hr] * cg1 + ce1, 0.f);
                *(ushort*)(h1t + hr*512 + (((col >> 3) ^ (hr & 15)) << 4) + (col & 7) * 2) = f2bf(r);
            }
        }
    __syncthreads();

    // ---- conv2 MFMA: 2 row-tiles ----
    f32x4 c2[2] = {};
    #pragma unroll
    for (int karm = 0; karm < 3; ++karm) {
        const ushort* bb = bpk2 + ((size_t)(karm * 16 + wv)) * 4096 + lane * 8;
        short8 bfr[8];
        #pragma unroll
        for (int s = 0; s < 8; ++s)
            bfr[s] = *reinterpret_cast<const short8*>(bb + s * 512);
        #pragma unroll
        for (int s = 0; s < 8; ++s) {
            #pragma unroll
            for (int tt = 0; tt < 2; ++tt) {
                int rA = 16 * tt + lr + karm;        // <= 33
                short8 a = *reinterpret_cast<const short8*>(
                    h1t + rA * 512 + ((((s << 2) + lg) ^ (rA & 15)) << 4));
                c2[tt] = __builtin_amdgcn_mfma_f32_16x16x32_bf16(a, bfr[s], c2[tt], 0, 0, 0);
            }
        }
    }

    // ---- conv2 stats ----
    const float cb2 = b2[col], cg2 = g2[col], ce2 = be2[col], clw = lw[col];
    {
        float sv[8], qv[8];
        #pragma unroll
        for (int tt = 0; tt < 2; ++tt)
            #pragma unroll
            for (int j = 0; j < 4; ++j) {
                float h = c2[tt][j] + cb2;
                sv[tt*4+j] = h; qv[tt*4+j] = h * h;
            }
        #pragma unroll
        for (int m = 1; m < 16; m <<= 1)
            #pragma unroll
            for (int k = 0; k < 8; ++k) {
                sv[k] += __shfl_xor(sv[k], m, 64);
                qv[k] += __shfl_xor(qv[k], m, 64);
            }
        if (lr == 0) {
            #pragma unroll
            for (int tt = 0; tt < 2; ++tt)
                #pragma unroll
                for (int j = 0; j < 4; ++j) {
                    redS[wv][16*tt + lg*4 + j] = sv[tt*4+j];
                    redQ[wv][16*tt + lg*4 + j] = qv[tt*4+j];
                }
        }
    }
    __syncthreads();
    if (tid < 32) {
        float ss = 0.f, qq = 0.f;
        #pragma unroll
        for (int u = 0; u < 16; ++u) { ss += redS[u][tid]; qq += redQ[u][tid]; }
        float m_  = ss * (1.f / 256.f);
        float var = fmaxf(qq * (1.f / 256.f) - m_ * m_, 0.f);
        redS[0][tid] = m_;
        redQ[0][tid] = 1.0f / sqrtf(var + EPSL);
    }
    __syncthreads();

    // ---- LN + ReLU + dot(lw) -> dur ----
    {
        float pv[8];
        #pragma unroll
        for (int tt = 0; tt < 2; ++tt)
            #pragma unroll
            for (int j = 0; j < 4; ++j) {
                int r = 16*tt + lg*4 + j;
                float rl = fmaxf((c2[tt][j] + cb2 - redS[0][r]) * redQ[0][r] * cg2 + ce2, 0.f);
                pv[tt*4+j] = rl * clw;
            }
        #pragma unroll
        for (int m = 1; m < 16; m <<= 1)
            #pragma unroll
            for (int k = 0; k < 8; ++k)
                pv[k] += __shfl_xor(pv[k], m, 64);
        if (lr == 0) {
            #pragma unroll
            for (int tt = 0; tt < 2; ++tt)
                #pragma unroll
                for (int j = 0; j < 4; ++j)
                    redP[wv][16*tt + lg*4 + j] = pv[tt*4+j];
        }
    }
    __syncthreads();
    if (tid < 32) {
        float dot = lb[0];
        #pragma unroll
        for (int u = 0; u < 16; ++u) dot += redP[u][tid];
        dur[n * L_ + l0 + tid] = (int)(fmaxf(dot, 0.f) + 0.5f);
    }
}

// ---------------------------------------------------------------------------
// per-batch inclusive scan (one wave per batch row) + WVF_pos tail
// ---------------------------------------------------------------------------
__global__ __launch_bounds__(64) void scan_pos_kernel(
    const int* __restrict__ dur, int* __restrict__ ends, float* __restrict__ wpos)
{
    const int n = blockIdx.x, lane = threadIdx.x;
    #pragma unroll
    for (int k = 0; k < 4; ++k) {
        int i = n * 256 + k * 64 + lane;
        wpos[i] = (float)(i + 1);
    }
    const int* dsrc = dur + n * L_;
    int4 va = reinterpret_cast<const int4*>(dsrc)[lane * 2];
    int4 vb = reinterpret_cast<const int4*>(dsrc)[lane * 2 + 1];
    int p0 = va.x,      p1 = p0 + va.y, p2 = p1 + va.z, p3 = p2 + va.w;
    int p4 = p3 + vb.x, p5 = p4 + vb.y, p6 = p5 + vb.z, p7 = p6 + vb.w;
    int tot = p7;
    #pragma unroll
    for (int m = 1; m < 64; m <<= 1) {
        int tu = __shfl_up(tot, m, 64);
        if (lane >= m) tot += tu;
    }
    int off = tot - p7;
    int* edst = ends + n * L_;
    int4 o1 = make_int4(p0 + off, p1 + off, p2 + off, p3 + off);
    int4 o2 = make_int4(p4 + off, p5 + off, p6 + off, p7 + off);
    reinterpret_cast<int4*>(edst)[lane * 2]     = o1;
    reinterpret_cast<int4*>(edst)[lane * 2 + 1] = o2;
}

// ---------------------------------------------------------------------------
// gather: wave-per-output-row; binary search over ends; nontemporal stores
// ---------------------------------------------------------------------------
__global__ __launch_bounds__(512) void gather_kernel(
    const float* __restrict__ x, const int* __restrict__ ends,
    float* __restrict__ out)
{
    const int wid = threadIdx.x >> 6, lane = threadIdx.x & 63;
    const int row = blockIdx.x * 8 + wid;   // row = n*T + t
    const int n = row >> 12;
    const int t = row & (T_ - 1);
    const int* e = ends + n * L_;
    const int total = e[L_ - 1];

    f32x4 v = {0.f, 0.f, 0.f, 0.f};
    if (t < total) {
        int p = 0;
        #pragma unroll
        for (int step = 256; step > 0; step >>= 1)
            if (p + step <= L_ && e[p + step - 1] <= t) p += step;
        v = reinterpret_cast<const f32x4*>(x + (((size_t)(n * L_ + p)) << 8))[lane];
    }
    __builtin_nontemporal_store(v, reinterpret_cast<f32x4*>(out + ((size_t)row << 8)) + lane);
}

// ---------------------------------------------------------------------------
extern "C" void kernel_launch(void* const* d_in, const int* in_sizes, int n_in,
                              void* d_out, int out_size, void* d_ws, size_t ws_size,
                              hipStream_t stream)
{
    const float* x   = (const float*)d_in[0];
    const float* w1  = (const float*)d_in[1];
    const float* b1  = (const float*)d_in[2];
    const float* g1  = (const float*)d_in[3];
    const float* be1 = (const float*)d_in[4];
    const float* w2  = (const float*)d_in[5];
    const float* b2  = (const float*)d_in[6];
    const float* g2  = (const float*)d_in[7];
    const float* be2 = (const float*)d_in[8];
    const float* lw  = (const float*)d_in[9];
    const float* lb  = (const float*)d_in[10];

    float* out = (float*)d_out;
    // weight-fragment scratch in d_out head (first 768 KB; gather overwrites)
    ushort* bpk1 = (ushort*)d_out;
    ushort* bpk2 = bpk1 + 196608;
    int* dur     = (int*)d_ws;
    int* ends    = dur + N_ * L_;

    pack_w_kernel<<<192, 256, 0, stream>>>(w1, w2, bpk1, bpk2);

    fused_conv_kernel<<<N_ * (L_ / BM), 1024, 0, stream>>>(
        x, bpk1, bpk2, b1, g1, be1, b2, g2, be2, lw, lb, dur);

    scan_pos_kernel<<<N_, 64, 0, stream>>>(dur, ends, out + (size_t)N_ * T_ * C_);

    gather_kernel<<<N_ * T_ / 8, 512, 0, stream>>>(x, ends, out);
}

// Round 8
// 41.210 us; speedup vs baseline: 1.6413x; 1.0198x over previous
//
#include <hip/hip_runtime.h>
#include <math.h>

#define N_   16
#define L_   512
#define C_   256
#define T_   4096
#define EPSL 1e-5f
#define BM   32           // dur rows per block

typedef short short8 __attribute__((ext_vector_type(8)));
typedef float f32x4  __attribute__((ext_vector_type(4)));

__device__ __forceinline__ ushort f2bf(float f) {
    union { float f; unsigned u; } v; v.f = f;
    return (ushort)((v.u + 0x7FFF + ((v.u >> 16) & 1)) >> 16);
}

// ---------------------------------------------------------------------------
// pack BOTH conv weights into MFMA B-fragment order (bf16) + write WVF_pos:
//   bpk[karm][cg(16)][s(8)][lane(64)][e(8)]
//   = w[karm][cin = s*32 + (lane>>4)*8 + e][cout = cg*16 + (lane&15)]
// ---------------------------------------------------------------------------
__global__ __launch_bounds__(256) void pack_w_kernel(
    const float* __restrict__ w1, const float* __restrict__ w2,
    ushort* __restrict__ bpk1, ushort* __restrict__ bpk2,
    float* __restrict__ wpos)
{
    int gid = blockIdx.x * 256 + threadIdx.x;        // 49152 total
    if (gid < T_) wpos[gid] = (float)(gid + 1);
    const float* w  = (gid < 24576) ? w1 : w2;
    ushort* bpk     = (gid < 24576) ? bpk1 : bpk2;
    int g2 = gid & 24575;
    int lane = g2 & 63;
    int s    = (g2 >> 6) & 7;
    int cg   = (g2 >> 9) & 15;
    int karm = g2 >> 13;
    int cin0 = s * 32 + (lane >> 4) * 8;
    int cout = cg * 16 + (lane & 15);
    const float* src = w + (size_t)(karm * 256 + cin0) * 256 + cout;
    short8 o;
    #pragma unroll
    for (int e = 0; e < 8; ++e) o[e] = (short)f2bf(src[(size_t)e * 256]);
    *reinterpret_cast<short8*>(bpk + (size_t)g2 * 8) = o;
}

// ---------------------------------------------------------------------------
// FUSED conv1+LN+ReLU -> conv2+LN+ReLU+linear -> dur.
// Block = 512 thr (8 waves) owns BM=32 dur rows; wave wv owns col-groups
// {2wv, 2wv+1} (32 couts) across ALL row-tiles -> each A ds_read feeds 2
// MFMAs; block B-traffic stays at exactly one weight copy (768 KB).
// ---------------------------------------------------------------------------
__global__ __launch_bounds__(512, 4) void fused_conv_kernel(
    const float* __restrict__ x,
    const ushort* __restrict__ bpk1, const ushort* __restrict__ bpk2,
    const float* __restrict__ b1, const float* __restrict__ g1, const float* __restrict__ be1,
    const float* __restrict__ b2, const float* __restrict__ g2, const float* __restrict__ be2,
    const float* __restrict__ lw, const float* __restrict__ lb,
    int* __restrict__ dur)
{
    // xt oversized to 50 rows: conv1 tile-2 A-reads touch rows up to 49; C rows
    // built from junk rows are discarded (C row r uses only lane-r's A data;
    // kept rows hr<=33 read staged rows <=35 only).
    __shared__ __align__(16) char xt[50 * 512];
    __shared__ __align__(16) char h1t[34 * 512];     // h1 rows l0-1 .. l0+32
    __shared__ float redS[8][48], redQ[8][48], redP[8][32];

    const int tid  = threadIdx.x;
    const int wv   = tid >> 6;                       // 0..7
    const int lane = tid & 63;
    const int lg   = lane >> 4;
    const int lr   = lane & 15;
    const int n    = blockIdx.x >> 4;
    const int l0   = (blockIdx.x & 15) << 5;
    const int cg0  = wv * 2;
    const int col0 = wv * 32 + lr, col1 = col0 + 16;

    // ---- stage x rows l0-2 .. l0+33 (36 rows), f32 -> bf16, XOR-swizzled ----
    for (int idx = tid; idx < 36 * 32; idx += 512) {
        int r = idx >> 5, slot = idx & 31;
        int l = l0 - 2 + r;
        short8 vb = {0,0,0,0,0,0,0,0};
        if (l >= 0 && l < L_) {
            const float* src = x + (((size_t)(n * L_ + l)) << 8) + (slot << 3);
            f32x4 f0 = *reinterpret_cast<const f32x4*>(src);
            f32x4 f1 = *reinterpret_cast<const f32x4*>(src + 4);
            vb[0]=(short)f2bf(f0[0]); vb[1]=(short)f2bf(f0[1]);
            vb[2]=(short)f2bf(f0[2]); vb[3]=(short)f2bf(f0[3]);
            vb[4]=(short)f2bf(f1[0]); vb[5]=(short)f2bf(f1[1]);
            vb[6]=(short)f2bf(f1[2]); vb[7]=(short)f2bf(f1[3]);
        }
        *reinterpret_cast<short8*>(xt + r * 512 + ((slot ^ (r & 15)) << 4)) = vb;
    }
    __syncthreads();

    // ---- conv1 MFMA: 3 row-tiles x 2 col-groups, B batched 4-deep ----
    f32x4 a1t[3][2] = {};
    #pragma unroll
    for (int karm = 0; karm < 3; ++karm) {
        const ushort* bb = bpk1 + ((size_t)(karm * 16 + cg0)) * 4096 + lane * 8;
        #pragma unroll
        for (int half = 0; half < 2; ++half) {
            short8 bf0[4], bf1[4];
            #pragma unroll
            for (int s4 = 0; s4 < 4; ++s4) {
                int s = half * 4 + s4;
                bf0[s4] = *reinterpret_cast<const short8*>(bb + s * 512);
                bf1[s4] = *reinterpret_cast<const short8*>(bb + 4096 + s * 512);
            }
            #pragma unroll
            for (int s4 = 0; s4 < 4; ++s4) {
                int s = half * 4 + s4;
                #pragma unroll
                for (int t = 0; t < 3; ++t) {
                    int rA = 16 * t + lr + karm;
                    short8 a = *reinterpret_cast<const short8*>(
                        xt + rA * 512 + ((((s << 2) + lg) ^ (rA & 15)) << 4));
                    a1t[t][0] = __builtin_amdgcn_mfma_f32_16x16x32_bf16(a, bf0[s4], a1t[t][0], 0, 0, 0);
                    a1t[t][1] = __builtin_amdgcn_mfma_f32_16x16x32_bf16(a, bf1[s4], a1t[t][1], 0, 0, 0);
                }
            }
        }
    }

    // ---- conv1 stats: shfl over 16 cols x 2cg, LDS combine over 8 waves ----
    const float cb10 = b1[col0], cb11 = b1[col1];
    const float cg10 = g1[col0], cg11 = g1[col1];
    const float ce10 = be1[col0], ce11 = be1[col1];
    {
        float sv[12], qv[12];
        #pragma unroll
        for (int t = 0; t < 3; ++t)
            #pragma unroll
            for (int j = 0; j < 4; ++j) {
                float h0 = a1t[t][0][j] + cb10, h1 = a1t[t][1][j] + cb11;
                sv[t*4+j] = h0 + h1; qv[t*4+j] = h0 * h0 + h1 * h1;
            }
        #pragma unroll
        for (int m = 1; m < 16; m <<= 1)
            #pragma unroll
            for (int k = 0; k < 12; ++k) {
                sv[k] += __shfl_xor(sv[k], m, 64);
                qv[k] += __shfl_xor(qv[k], m, 64);
            }
        if (lr == 0) {
            #pragma unroll
            for (int t = 0; t < 3; ++t)
                #pragma unroll
                for (int j = 0; j < 4; ++j) {
                    redS[wv][16*t + lg*4 + j] = sv[t*4+j];
                    redQ[wv][16*t + lg*4 + j] = qv[t*4+j];
                }
        }
    }
    __syncthreads();
    if (tid < 48) {
        float ss = 0.f, qq = 0.f;
        #pragma unroll
        for (int u = 0; u < 8; ++u) { ss += redS[u][tid]; qq += redQ[u][tid]; }
        float m_  = ss * (1.f / 256.f);
        float var = fmaxf(qq * (1.f / 256.f) - m_ * m_, 0.f);
        redS[0][tid] = m_;
        redQ[0][tid] = 1.0f / sqrtf(var + EPSL);
    }
    __syncthreads();

    // ---- normalize + ReLU -> h1t (rows 0..33 kept) ----
    #pragma unroll
    for (int t = 0; t < 3; ++t)
        #pragma unroll
        for (int j = 0; j < 4; ++j) {
            int hr = 16*t + lg*4 + j;
            if (hr < 34) {
                int hl = l0 - 1 + hr;
                float r0 = 0.f, r1 = 0.f;
                if (hl >= 0 && hl < L_) {
                    r0 = fmaxf((a1t[t][0][j] + cb10 - redS[0][hr]) * redQ[0][hr] * cg10 + ce10, 0.f);
                    r1 = fmaxf((a1t[t][1][j] + cb11 - redS[0][hr]) * redQ[0][hr] * cg11 + ce11, 0.f);
                }
                *(ushort*)(h1t + hr*512 + (((col0 >> 3) ^ (hr & 15)) << 4) + (col0 & 7) * 2) = f2bf(r0);
                *(ushort*)(h1t + hr*512 + (((col1 >> 3) ^ (hr & 15)) << 4) + (col1 & 7) * 2) = f2bf(r1);
            }
        }
    __syncthreads();

    // ---- conv2 MFMA: 2 row-tiles x 2 col-groups ----
    f32x4 c2[2][2] = {};
    #pragma unroll
    for (int karm = 0; karm < 3; ++karm) {
        const ushort* bb = bpk2 + ((size_t)(karm * 16 + cg0)) * 4096 + lane * 8;
        #pragma unroll
        for (int half = 0; half < 2; ++half) {
            short8 bf0[4], bf1[4];
            #pragma unroll
            for (int s4 = 0; s4 < 4; ++s4) {
                int s = half * 4 + s4;
                bf0[s4] = *reinterpret_cast<const short8*>(bb + s * 512);
                bf1[s4] = *reinterpret_cast<const short8*>(bb + 4096 + s * 512);
            }
            #pragma unroll
            for (int s4 = 0; s4 < 4; ++s4) {
                int s = half * 4 + s4;
                #pragma unroll
                for (int tt = 0; tt < 2; ++tt) {
                    int rA = 16 * tt + lr + karm;    // <= 33
                    short8 a = *reinterpret_cast<const short8*>(
                        h1t + rA * 512 + ((((s << 2) + lg) ^ (rA & 15)) << 4));
                    c2[tt][0] = __builtin_amdgcn_mfma_f32_16x16x32_bf16(a, bf0[s4], c2[tt][0], 0, 0, 0);
                    c2[tt][1] = __builtin_amdgcn_mfma_f32_16x16x32_bf16(a, bf1[s4], c2[tt][1], 0, 0, 0);
                }
            }
        }
    }

    // ---- conv2 stats ----
    const float cb20 = b2[col0], cb21 = b2[col1];
    const float cg20 = g2[col0], cg21 = g2[col1];
    const float ce20 = be2[col0], ce21 = be2[col1];
    const float lw0  = lw[col0],  lw1  = lw[col1];
    {
        float sv[8], qv[8];
        #pragma unroll
        for (int tt = 0; tt < 2; ++tt)
            #pragma unroll
            for (int j = 0; j < 4; ++j) {
                float h0 = c2[tt][0][j] + cb20, h1 = c2[tt][1][j] + cb21;
                sv[tt*4+j] = h0 + h1; qv[tt*4+j] = h0 * h0 + h1 * h1;
            }
        #pragma unroll
        for (int m = 1; m < 16; m <<= 1)
            #pragma unroll
            for (int k = 0; k < 8; ++k) {
                sv[k] += __shfl_xor(sv[k], m, 64);
                qv[k] += __shfl_xor(qv[k], m, 64);
            }
        if (lr == 0) {
            #pragma unroll
            for (int tt = 0; tt < 2; ++tt)
                #pragma unroll
                for (int j = 0; j < 4; ++j) {
                    redS[wv][16*tt + lg*4 + j] = sv[tt*4+j];
                    redQ[wv][16*tt + lg*4 + j] = qv[tt*4+j];
                }
        }
    }
    __syncthreads();
    if (tid < 32) {
        float ss = 0.f, qq = 0.f;
        #pragma unroll
        for (int u = 0; u < 8; ++u) { ss += redS[u][tid]; qq += redQ[u][tid]; }
        float m_  = ss * (1.f / 256.f);
        float var = fmaxf(qq * (1.f / 256.f) - m_ * m_, 0.f);
        redS[0][tid] = m_;
        redQ[0][tid] = 1.0f / sqrtf(var + EPSL);
    }
    __syncthreads();

    // ---- LN + ReLU + dot(lw) -> dur ----
    {
        float pv[8];
        #pragma unroll
        for (int tt = 0; tt < 2; ++tt)
            #pragma unroll
            for (int j = 0; j < 4; ++j) {
                int r = 16*tt + lg*4 + j;
                float r0 = fmaxf((c2[tt][0][j] + cb20 - redS[0][r]) * redQ[0][r] * cg20 + ce20, 0.f);
                float r1 = fmaxf((c2[tt][1][j] + cb21 - redS[0][r]) * redQ[0][r] * cg21 + ce21, 0.f);
                pv[tt*4+j] = r0 * lw0 + r1 * lw1;
            }
        #pragma unroll
        for (int m = 1; m < 16; m <<= 1)
            #pragma unroll
            for (int k = 0; k < 8; ++k)
                pv[k] += __shfl_xor(pv[k], m, 64);
        if (lr == 0) {
            #pragma unroll
            for (int tt = 0; tt < 2; ++tt)
                #pragma unroll
                for (int j = 0; j < 4; ++j)
                    redP[wv][16*tt + lg*4 + j] = pv[tt*4+j];
        }
    }
    __syncthreads();
    if (tid < 32) {
        float dot = lb[0];
        #pragma unroll
        for (int u = 0; u < 8; ++u) dot += redP[u][tid];
        dur[n * L_ + l0 + tid] = (int)(fmaxf(dot, 0.f) + 0.5f);
    }
}

// ---------------------------------------------------------------------------
// gather: inline per-block scan of dur (wave 0) -> LDS ends; 8 rows/block;
// binary search in LDS; nontemporal float4 stores.
// ---------------------------------------------------------------------------
__global__ __launch_bounds__(512) void gather_kernel(
    const float* __restrict__ x, const int* __restrict__ dur,
    float* __restrict__ out)
{
    __shared__ __align__(16) int se[L_];
    const int wid = threadIdx.x >> 6, lane = threadIdx.x & 63;
    const int blk = blockIdx.x;
    const int n = blk >> 9;                 // 512 blocks per batch row

    if (wid == 0) {
        const int* dsrc = dur + n * L_;
        int4 va = reinterpret_cast<const int4*>(dsrc)[lane * 2];
        int4 vb = reinterpret_cast<const int4*>(dsrc)[lane * 2 + 1];
        int p0 = va.x,      p1 = p0 + va.y, p2 = p1 + va.z, p3 = p2 + va.w;
        int p4 = p3 + vb.x, p5 = p4 + vb.y, p6 = p5 + vb.z, p7 = p6 + vb.w;
        int tot = p7;
        #pragma unroll
        for (int m = 1; m < 64; m <<= 1) {
            int tu = __shfl_up(tot, m, 64);
            if (lane >= m) tot += tu;
        }
        int off = tot - p7;
        reinterpret_cast<int4*>(se)[lane * 2]     = make_int4(p0+off, p1+off, p2+off, p3+off);
        reinterpret_cast<int4*>(se)[lane * 2 + 1] = make_int4(p4+off, p5+off, p6+off, p7+off);
    }
    __syncthreads();

    const int t = ((blk & 511) << 3) + wid;
    const int total = se[L_ - 1];

    f32x4 v = {0.f, 0.f, 0.f, 0.f};
    if (t < total) {
        int p = 0;
        #pragma unroll
        for (int step = 256; step > 0; step >>= 1)
            if (p + step <= L_ && se[p + step - 1] <= t) p += step;
        v = reinterpret_cast<const f32x4*>(x + (((size_t)(n * L_ + p)) << 8))[lane];
    }
    __builtin_nontemporal_store(
        v, reinterpret_cast<f32x4*>(out + (((size_t)(n * T_ + t)) << 8)) + lane);
}

// ---------------------------------------------------------------------------
extern "C" void kernel_launch(void* const* d_in, const int* in_sizes, int n_in,
                              void* d_out, int out_size, void* d_ws, size_t ws_size,
                              hipStream_t stream)
{
    const float* x   = (const float*)d_in[0];
    const float* w1  = (const float*)d_in[1];
    const float* b1  = (const float*)d_in[2];
    const float* g1  = (const float*)d_in[3];
    const float* be1 = (const float*)d_in[4];
    const float* w2  = (const float*)d_in[5];
    const float* b2  = (const float*)d_in[6];
    const float* g2  = (const float*)d_in[7];
    const float* be2 = (const float*)d_in[8];
    const float* lw  = (const float*)d_in[9];
    const float* lb  = (const float*)d_in[10];

    float* out = (float*)d_out;
    // weight-fragment scratch in d_out head (first 768 KB; gather overwrites)
    ushort* bpk1 = (ushort*)d_out;
    ushort* bpk2 = bpk1 + 196608;
    int* dur     = (int*)d_ws;

    pack_w_kernel<<<192, 256, 0, stream>>>(w1, w2, bpk1, bpk2,
                                           out + (size_t)N_ * T_ * C_);

    fused_conv_kernel<<<N_ * (L_ / BM), 512, 0, stream>>>(
        x, bpk1, bpk2, b1, g1, be1, b2, g2, be2, lw, lb, dur);

    gather_kernel<<<N_ * T_ / 8, 512, 0, stream>>>(x, dur, out);
}

// Round 9
// 38.732 us; speedup vs baseline: 1.7464x; 1.0640x over previous
//
#include <hip/hip_runtime.h>
#include <math.h>

#define N_   16
#define L_   512
#define C_   256
#define T_   4096
#define EPSL 1e-5f
#define BM   32           // dur rows per block

typedef short short8 __attribute__((ext_vector_type(8)));
typedef float f32x4  __attribute__((ext_vector_type(4)));

__device__ __forceinline__ ushort f2bf(float f) {
    union { float f; unsigned u; } v; v.f = f;
    return (ushort)((v.u + 0x7FFF + ((v.u >> 16) & 1)) >> 16);
}

// ---------------------------------------------------------------------------
// pack BOTH conv weights into MFMA B-fragment order (bf16) + write WVF_pos:
//   bpk[karm][cg(16)][s(8)][lane(64)][e(8)]
//   = w[karm][cin = s*32 + (lane>>4)*8 + e][cout = cg*16 + (lane&15)]
// ---------------------------------------------------------------------------
__global__ __launch_bounds__(256) void pack_w_kernel(
    const float* __restrict__ w1, const float* __restrict__ w2,
    ushort* __restrict__ bpk1, ushort* __restrict__ bpk2,
    float* __restrict__ wpos)
{
    int gid = blockIdx.x * 256 + threadIdx.x;        // 49152 total
    if (gid < T_) wpos[gid] = (float)(gid + 1);
    const float* w  = (gid < 24576) ? w1 : w2;
    ushort* bpk     = (gid < 24576) ? bpk1 : bpk2;
    int g2 = gid & 24575;
    int lane = g2 & 63;
    int s    = (g2 >> 6) & 7;
    int cg   = (g2 >> 9) & 15;
    int karm = g2 >> 13;
    int cin0 = s * 32 + (lane >> 4) * 8;
    int cout = cg * 16 + (lane & 15);
    const float* src = w + (size_t)(karm * 256 + cin0) * 256 + cout;
    short8 o;
    #pragma unroll
    for (int e = 0; e < 8; ++e) o[e] = (short)f2bf(src[(size_t)e * 256]);
    *reinterpret_cast<short8*>(bpk + (size_t)g2 * 8) = o;
}

// ---- B-fragment prefetch (16 frags = 2 col-groups x 8 k-slices) ----
#define LDB(BPK, KARM, DST) do {                                              \
    const ushort* bb_ = (BPK) + ((size_t)((KARM) * 16 + cg0)) * 4096 + lane * 8; \
    _Pragma("unroll")                                                         \
    for (int s_ = 0; s_ < 8; ++s_) {                                          \
        DST[s_]     = *reinterpret_cast<const short8*>(bb_ + s_ * 512);       \
        DST[8 + s_] = *reinterpret_cast<const short8*>(bb_ + 4096 + s_ * 512);\
    } } while (0)

// ---- one karm of conv1: 3 row-tiles x 2 col-groups = 48 MFMAs ----
#define CONV1K(KARM, B) do {                                                  \
    _Pragma("unroll")                                                         \
    for (int s_ = 0; s_ < 8; ++s_) {                                          \
        _Pragma("unroll")                                                     \
        for (int t_ = 0; t_ < 3; ++t_) {                                      \
            int rA_ = 16 * t_ + lr + (KARM);                                  \
            short8 a_ = *reinterpret_cast<const short8*>(                     \
                xt + rA_ * 512 + ((((s_ << 2) + lg) ^ (rA_ & 15)) << 4));     \
            acc1[t_][0] = __builtin_amdgcn_mfma_f32_16x16x32_bf16(a_, B[s_],     acc1[t_][0], 0, 0, 0); \
            acc1[t_][1] = __builtin_amdgcn_mfma_f32_16x16x32_bf16(a_, B[8 + s_], acc1[t_][1], 0, 0, 0); \
        } } } while (0)

// ---- one karm of conv2: 2 row-tiles x 2 col-groups = 32 MFMAs ----
#define CONV2K(KARM, B) do {                                                  \
    _Pragma("unroll")                                                         \
    for (int s_ = 0; s_ < 8; ++s_) {                                          \
        _Pragma("unroll")                                                     \
        for (int t_ = 0; t_ < 2; ++t_) {                                      \
            int rA_ = 16 * t_ + lr + (KARM);                                  \
            short8 a_ = *reinterpret_cast<const short8*>(                     \
                h1t + rA_ * 512 + ((((s_ << 2) + lg) ^ (rA_ & 15)) << 4));    \
            c2[t_][0] = __builtin_amdgcn_mfma_f32_16x16x32_bf16(a_, B[s_],     c2[t_][0], 0, 0, 0); \
            c2[t_][1] = __builtin_amdgcn_mfma_f32_16x16x32_bf16(a_, B[8 + s_], c2[t_][1], 0, 0, 0); \
        } } } while (0)

// ---------------------------------------------------------------------------
// FUSED conv1+LN+ReLU -> conv2+LN+ReLU+linear -> dur.
// Block = 512 thr (8 waves) owns BM=32 dur rows; wave wv owns col-groups
// {2wv, 2wv+1}. B-fragments double-buffered in registers (Ba/Bb), each
// karm's loads issued one stage ahead so the L2 round-trip hides under the
// previous karm's 48 MFMAs. No min-wave launch bound: grid=256 -> 1 block/CU,
// 2 waves/SIMD fixed; give the allocator the full register budget.
// ---------------------------------------------------------------------------
__global__ __launch_bounds__(512) void fused_conv_kernel(
    const float* __restrict__ x,
    const ushort* __restrict__ bpk1, const ushort* __restrict__ bpk2,
    const float* __restrict__ b1, const float* __restrict__ g1, const float* __restrict__ be1,
    const float* __restrict__ b2, const float* __restrict__ g2, const float* __restrict__ be2,
    const float* __restrict__ lw, const float* __restrict__ lb,
    int* __restrict__ dur)
{
    // xt oversized to 50 rows: conv1 tile-2 A-reads touch rows up to 49; C rows
    // built from junk rows are discarded (kept rows hr<=33 use staged rows <=35).
    __shared__ __align__(16) char xt[50 * 512];
    __shared__ __align__(16) char h1t[34 * 512];     // h1 rows l0-1 .. l0+32
    __shared__ float redS[8][48], redQ[8][48], redP[8][32];

    const int tid  = threadIdx.x;
    const int wv   = tid >> 6;                       // 0..7
    const int lane = tid & 63;
    const int lg   = lane >> 4;
    const int lr   = lane & 15;
    const int n    = blockIdx.x >> 4;
    const int l0   = (blockIdx.x & 15) << 5;
    const int cg0  = wv * 2;
    const int col0 = wv * 32 + lr, col1 = col0 + 16;

    short8 Ba[16], Bb[16];
    LDB(bpk1, 0, Ba);                                // in flight during stage

    // ---- stage x rows l0-2 .. l0+33 (36 rows), f32 -> bf16, XOR-swizzled ----
    for (int idx = tid; idx < 36 * 32; idx += 512) {
        int r = idx >> 5, slot = idx & 31;
        int l = l0 - 2 + r;
        short8 vb = {0,0,0,0,0,0,0,0};
        if (l >= 0 && l < L_) {
            const float* src = x + (((size_t)(n * L_ + l)) << 8) + (slot << 3);
            f32x4 f0 = *reinterpret_cast<const f32x4*>(src);
            f32x4 f1 = *reinterpret_cast<const f32x4*>(src + 4);
            vb[0]=(short)f2bf(f0[0]); vb[1]=(short)f2bf(f0[1]);
            vb[2]=(short)f2bf(f0[2]); vb[3]=(short)f2bf(f0[3]);
            vb[4]=(short)f2bf(f1[0]); vb[5]=(short)f2bf(f1[1]);
            vb[6]=(short)f2bf(f1[2]); vb[7]=(short)f2bf(f1[3]);
        }
        *reinterpret_cast<short8*>(xt + r * 512 + ((slot ^ (r & 15)) << 4)) = vb;
    }
    __syncthreads();

    // ---- conv1: software-pipelined karm loop ----
    f32x4 acc1[3][2] = {};
    LDB(bpk1, 1, Bb);  CONV1K(0, Ba);
    LDB(bpk1, 2, Ba);  CONV1K(1, Bb);
    LDB(bpk2, 0, Bb);  CONV1K(2, Ba);
    LDB(bpk2, 1, Ba);                                // hides under epilogue

    // ---- conv1 stats: shfl over 16 cols x 2cg, LDS combine over 8 waves ----
    const float cb10 = b1[col0], cb11 = b1[col1];
    const float cg10 = g1[col0], cg11 = g1[col1];
    const float ce10 = be1[col0], ce11 = be1[col1];
    {
        float sv[12], qv[12];
        #pragma unroll
        for (int t = 0; t < 3; ++t)
            #pragma unroll
            for (int j = 0; j < 4; ++j) {
                float h0 = acc1[t][0][j] + cb10, h1 = acc1[t][1][j] + cb11;
                sv[t*4+j] = h0 + h1; qv[t*4+j] = h0 * h0 + h1 * h1;
            }
        #pragma unroll
        for (int m = 1; m < 16; m <<= 1)
            #pragma unroll
            for (int k = 0; k < 12; ++k) {
                sv[k] += __shfl_xor(sv[k], m, 64);
                qv[k] += __shfl_xor(qv[k], m, 64);
            }
        if (lr == 0) {
            #pragma unroll
            for (int t = 0; t < 3; ++t)
                #pragma unroll
                for (int j = 0; j < 4; ++j) {
                    redS[wv][16*t + lg*4 + j] = sv[t*4+j];
                    redQ[wv][16*t + lg*4 + j] = qv[t*4+j];
                }
        }
    }
    __syncthreads();
    if (tid < 48) {
        float ss = 0.f, qq = 0.f;
        #pragma unroll
        for (int u = 0; u < 8; ++u) { ss += redS[u][tid]; qq += redQ[u][tid]; }
        float m_  = ss * (1.f / 256.f);
        float var = fmaxf(qq * (1.f / 256.f) - m_ * m_, 0.f);
        redS[0][tid] = m_;
        redQ[0][tid] = 1.0f / sqrtf(var + EPSL);
    }
    __syncthreads();

    // ---- normalize + ReLU -> h1t (rows 0..33 kept) ----
    #pragma unroll
    for (int t = 0; t < 3; ++t)
        #pragma unroll
        for (int j = 0; j < 4; ++j) {
            int hr = 16*t + lg*4 + j;
            if (hr < 34) {
                int hl = l0 - 1 + hr;
                float r0 = 0.f, r1 = 0.f;
                if (hl >= 0 && hl < L_) {
                    r0 = fmaxf((acc1[t][0][j] + cb10 - redS[0][hr]) * redQ[0][hr] * cg10 + ce10, 0.f);
                    r1 = fmaxf((acc1[t][1][j] + cb11 - redS[0][hr]) * redQ[0][hr] * cg11 + ce11, 0.f);
                }
                *(ushort*)(h1t + hr*512 + (((col0 >> 3) ^ (hr & 15)) << 4) + (col0 & 7) * 2) = f2bf(r0);
                *(ushort*)(h1t + hr*512 + (((col1 >> 3) ^ (hr & 15)) << 4) + (col1 & 7) * 2) = f2bf(r1);
            }
        }
    __syncthreads();

    // ---- conv2: software-pipelined karm loop (Bb holds k0, Ba holds k1) ----
    f32x4 c2[2][2] = {};
    CONV2K(0, Bb);  LDB(bpk2, 2, Bb);
    CONV2K(1, Ba);
    CONV2K(2, Bb);

    // ---- conv2 stats ----
    const float cb20 = b2[col0], cb21 = b2[col1];
    const float cg20 = g2[col0], cg21 = g2[col1];
    const float ce20 = be2[col0], ce21 = be2[col1];
    const float lw0  = lw[col0],  lw1  = lw[col1];
    {
        float sv[8], qv[8];
        #pragma unroll
        for (int tt = 0; tt < 2; ++tt)
            #pragma unroll
            for (int j = 0; j < 4; ++j) {
                float h0 = c2[tt][0][j] + cb20, h1 = c2[tt][1][j] + cb21;
                sv[tt*4+j] = h0 + h1; qv[tt*4+j] = h0 * h0 + h1 * h1;
            }
        #pragma unroll
        for (int m = 1; m < 16; m <<= 1)
            #pragma unroll
            for (int k = 0; k < 8; ++k) {
                sv[k] += __shfl_xor(sv[k], m, 64);
                qv[k] += __shfl_xor(qv[k], m, 64);
            }
        if (lr == 0) {
            #pragma unroll
            for (int tt = 0; tt < 2; ++tt)
                #pragma unroll
                for (int j = 0; j < 4; ++j) {
                    redS[wv][16*tt + lg*4 + j] = sv[tt*4+j];
                    redQ[wv][16*tt + lg*4 + j] = qv[tt*4+j];
                }
        }
    }
    __syncthreads();
    if (tid < 32) {
        float ss = 0.f, qq = 0.f;
        #pragma unroll
        for (int u = 0; u < 8; ++u) { ss += redS[u][tid]; qq += redQ[u][tid]; }
        float m_  = ss * (1.f / 256.f);
        float var = fmaxf(qq * (1.f / 256.f) - m_ * m_, 0.f);
        redS[0][tid] = m_;
        redQ[0][tid] = 1.0f / sqrtf(var + EPSL);
    }
    __syncthreads();

    // ---- LN + ReLU + dot(lw) -> dur ----
    {
        float pv[8];
        #pragma unroll
        for (int tt = 0; tt < 2; ++tt)
            #pragma unroll
            for (int j = 0; j < 4; ++j) {
                int r = 16*tt + lg*4 + j;
                float r0 = fmaxf((c2[tt][0][j] + cb20 - redS[0][r]) * redQ[0][r] * cg20 + ce20, 0.f);
                float r1 = fmaxf((c2[tt][1][j] + cb21 - redS[0][r]) * redQ[0][r] * cg21 + ce21, 0.f);
                pv[tt*4+j] = r0 * lw0 + r1 * lw1;
            }
        #pragma unroll
        for (int m = 1; m < 16; m <<= 1)
            #pragma unroll
            for (int k = 0; k < 8; ++k)
                pv[k] += __shfl_xor(pv[k], m, 64);
        if (lr == 0) {
            #pragma unroll
            for (int tt = 0; tt < 2; ++tt)
                #pragma unroll
                for (int j = 0; j < 4; ++j)
                    redP[wv][16*tt + lg*4 + j] = pv[tt*4+j];
        }
    }
    __syncthreads();
    if (tid < 32) {
        float dot = lb[0];
        #pragma unroll
        for (int u = 0; u < 8; ++u) dot += redP[u][tid];
        dur[n * L_ + l0 + tid] = (int)(fmaxf(dot, 0.f) + 0.5f);
    }
}

// ---------------------------------------------------------------------------
// gather: inline per-block scan of dur (wave 0) -> LDS ends; 8 rows/block;
// binary search in LDS; nontemporal float4 stores.
// ---------------------------------------------------------------------------
__global__ __launch_bounds__(512) void gather_kernel(
    const float* __restrict__ x, const int* __restrict__ dur,
    float* __restrict__ out)
{
    __shared__ __align__(16) int se[L_];
    const int wid = threadIdx.x >> 6, lane = threadIdx.x & 63;
    const int blk = blockIdx.x;
    const int n = blk >> 9;                 // 512 blocks per batch row

    if (wid == 0) {
        const int* dsrc = dur + n * L_;
        int4 va = reinterpret_cast<const int4*>(dsrc)[lane * 2];
        int4 vb = reinterpret_cast<const int4*>(dsrc)[lane * 2 + 1];
        int p0 = va.x,      p1 = p0 + va.y, p2 = p1 + va.z, p3 = p2 + va.w;
        int p4 = p3 + vb.x, p5 = p4 + vb.y, p6 = p5 + vb.z, p7 = p6 + vb.w;
        int tot = p7;
        #pragma unroll
        for (int m = 1; m < 64; m <<= 1) {
            int tu = __shfl_up(tot, m, 64);
            if (lane >= m) tot += tu;
        }
        int off = tot - p7;
        reinterpret_cast<int4*>(se)[lane * 2]     = make_int4(p0+off, p1+off, p2+off, p3+off);
        reinterpret_cast<int4*>(se)[lane * 2 + 1] = make_int4(p4+off, p5+off, p6+off, p7+off);
    }
    __syncthreads();

    const int t = ((blk & 511) << 3) + wid;
    const int total = se[L_ - 1];

    f32x4 v = {0.f, 0.f, 0.f, 0.f};
    if (t < total) {
        int p = 0;
        #pragma unroll
        for (int step = 256; step > 0; step >>= 1)
            if (p + step <= L_ && se[p + step - 1] <= t) p += step;
        v = reinterpret_cast<const f32x4*>(x + (((size_t)(n * L_ + p)) << 8))[lane];
    }
    __builtin_nontemporal_store(
        v, reinterpret_cast<f32x4*>(out + (((size_t)(n * T_ + t)) << 8)) + lane);
}

// ---------------------------------------------------------------------------
extern "C" void kernel_launch(void* const* d_in, const int* in_sizes, int n_in,
                              void* d_out, int out_size, void* d_ws, size_t ws_size,
                              hipStream_t stream)
{
    const float* x   = (const float*)d_in[0];
    const float* w1  = (const float*)d_in[1];
    const float* b1  = (const float*)d_in[2];
    const float* g1  = (const float*)d_in[3];
    const float* be1 = (const float*)d_in[4];
    const float* w2  = (const float*)d_in[5];
    const float* b2  = (const float*)d_in[6];
    const float* g2  = (const float*)d_in[7];
    const float* be2 = (const float*)d_in[8];
    const float* lw  = (const float*)d_in[9];
    const float* lb  = (const float*)d_in[10];

    float* out = (float*)d_out;
    // weight-fragment scratch in d_out head (first 768 KB; gather overwrites)
    ushort* bpk1 = (ushort*)d_out;
    ushort* bpk2 = bpk1 + 196608;
    int* dur     = (int*)d_ws;

    pack_w_kernel<<<192, 256, 0, stream>>>(w1, w2, bpk1, bpk2,
                                           out + (size_t)N_ * T_ * C_);

    fused_conv_kernel<<<N_ * (L_ / BM), 512, 0, stream>>>(
        x, bpk1, bpk2, b1, g1, be1, b2, g2, be2, lw, lb, dur);

    gather_kernel<<<N_ * T_ / 8, 512, 0, stream>>>(x, dur, out);
}

// Round 10
// 37.249 us; speedup vs baseline: 1.8159x; 1.0398x over previous
//
#include <hip/hip_runtime.h>
#include <hip/hip_fp8.h>
#include <math.h>

#define N_   16
#define L_   512
#define C_   256
#define T_   4096
#define EPSL 1e-5f
#define BM   32           // dur rows per block

typedef float f32x4 __attribute__((ext_vector_type(4)));

__device__ __forceinline__ unsigned char f2q(float f) {
    __hip_fp8_e4m3 q(f);
    return (unsigned char)q.__x;
}

// ---------------------------------------------------------------------------
// pack BOTH conv weights into fp8 MFMA B-fragment order + write WVF_pos:
//   bpk[karm][cg(16)][s(8)][lane(64)][e(8 bytes)]
//   = fp8(w[karm][cin = s*32 + (lane>>4)*8 + e][cout = cg*16 + (lane&15)])
// ---------------------------------------------------------------------------
__global__ __launch_bounds__(256) void pack_w_kernel(
    const float* __restrict__ w1, const float* __restrict__ w2,
    unsigned char* __restrict__ bpk1, unsigned char* __restrict__ bpk2,
    float* __restrict__ wpos)
{
    int gid = blockIdx.x * 256 + threadIdx.x;        // 49152 total
    if (gid < T_) wpos[gid] = (float)(gid + 1);
    const float* w      = (gid < 24576) ? w1 : w2;
    unsigned char* bpk  = (gid < 24576) ? bpk1 : bpk2;
    int g2 = gid & 24575;
    int lane = g2 & 63;
    int s    = (g2 >> 6) & 7;
    int cg   = (g2 >> 9) & 15;
    int karm = g2 >> 13;
    int cin0 = s * 32 + (lane >> 4) * 8;
    int cout = cg * 16 + (lane & 15);
    const float* src = w + (size_t)(karm * 256 + cin0) * 256 + cout;
    unsigned long long o = 0;
    #pragma unroll
    for (int e = 0; e < 8; ++e)
        o |= (unsigned long long)f2q(src[(size_t)e * 256]) << (8 * e);
    *reinterpret_cast<unsigned long long*>(bpk + (size_t)g2 * 8) = o;
}

// ---- B-fragment prefetch: 16 frags (2 col-groups x 8 k-slices), 8B each ----
#define LDB(BPK, KARM, DST) do {                                              \
    const unsigned char* bb_ = (BPK) + ((size_t)((KARM) * 16 + cg0)) * 4096 + lane * 8; \
    _Pragma("unroll")                                                         \
    for (int s_ = 0; s_ < 8; ++s_) {                                          \
        DST[s_]     = *reinterpret_cast<const long*>(bb_ + s_ * 512);         \
        DST[8 + s_] = *reinterpret_cast<const long*>(bb_ + 4096 + s_ * 512);  \
    } } while (0)

// A-fragment LDS byte offset (fp8): row rA, k-slice s, k-group lg.
#define AOFF(BUF, RA, S)                                                      \
    (BUF + (RA) * 256 + (((((S) << 1) + (lg >> 1)) ^ ((RA) & 15)) << 4) + ((lg & 1) << 3))

// ---- one karm of conv1: 3 row-tiles x 2 col-groups = 48 MFMAs ----
#define CONV1K(KARM, B) do {                                                  \
    _Pragma("unroll")                                                         \
    for (int s_ = 0; s_ < 8; ++s_) {                                          \
        _Pragma("unroll")                                                     \
        for (int t_ = 0; t_ < 3; ++t_) {                                      \
            int rA_ = 16 * t_ + lr + (KARM);                                  \
            long a_ = *reinterpret_cast<const long*>(AOFF(xt, rA_, s_));      \
            acc1[t_][0] = __builtin_amdgcn_mfma_f32_16x16x32_fp8_fp8(a_, B[s_],     acc1[t_][0], 0, 0, 0); \
            acc1[t_][1] = __builtin_amdgcn_mfma_f32_16x16x32_fp8_fp8(a_, B[8 + s_], acc1[t_][1], 0, 0, 0); \
        } } } while (0)

// ---- one karm of conv2: 2 row-tiles x 2 col-groups = 32 MFMAs ----
#define CONV2K(KARM, B) do {                                                  \
    _Pragma("unroll")                                                         \
    for (int s_ = 0; s_ < 8; ++s_) {                                          \
        _Pragma("unroll")                                                     \
        for (int t_ = 0; t_ < 2; ++t_) {                                      \
            int rA_ = 16 * t_ + lr + (KARM);                                  \
            long a_ = *reinterpret_cast<const long*>(AOFF(h1t, rA_, s_));     \
            c2[t_][0] = __builtin_amdgcn_mfma_f32_16x16x32_fp8_fp8(a_, B[s_],     c2[t_][0], 0, 0, 0); \
            c2[t_][1] = __builtin_amdgcn_mfma_f32_16x16x32_fp8_fp8(a_, B[8 + s_], c2[t_][1], 0, 0, 0); \
        } } } while (0)

// ---------------------------------------------------------------------------
// FUSED conv1+LN+ReLU -> conv2+LN+ReLU+linear -> dur, all fp8 MFMA.
// Block = 512 thr (8 waves) owns BM=32 dur rows; wave wv owns col-groups
// {2wv, 2wv+1}. B double-buffered in registers (now 32+32 longs = 64 VGPR).
// xt rows 36..49 are never written; they feed only DISCARDED C rows of
// conv1 tile-2 (kept rows 32,33 read staged rows <= 35).
// ---------------------------------------------------------------------------
__global__ __launch_bounds__(512) void fused_conv_kernel(
    const float* __restrict__ x,
    const unsigned char* __restrict__ bpk1, const unsigned char* __restrict__ bpk2,
    const float* __restrict__ b1, const float* __restrict__ g1, const float* __restrict__ be1,
    const float* __restrict__ b2, const float* __restrict__ g2, const float* __restrict__ be2,
    const float* __restrict__ lw, const float* __restrict__ lb,
    int* __restrict__ dur)
{
    __shared__ __align__(16) char xt[50 * 256];      // fp8 rows l0-2 .. (36 staged)
    __shared__ __align__(16) char h1t[34 * 256];     // fp8 h1 rows l0-1 .. l0+32
    __shared__ float redS[8][48], redQ[8][48], redP[8][32];

    const int tid  = threadIdx.x;
    const int wv   = tid >> 6;                       // 0..7
    const int lane = tid & 63;
    const int lg   = lane >> 4;
    const int lr   = lane & 15;
    const int n    = blockIdx.x >> 4;
    const int l0   = (blockIdx.x & 15) << 5;
    const int cg0  = wv * 2;
    const int col0 = wv * 32 + lr, col1 = col0 + 16;

    long Ba[16], Bb[16];
    LDB(bpk1, 0, Ba);                                // in flight during stage

    // ---- stage x rows l0-2 .. l0+33 (36 rows), f32 -> fp8, XOR-swizzled ----
    for (int idx = tid; idx < 36 * 16; idx += 512) { // 16B chunk = 16 cols
        int r = idx >> 4, slot = idx & 15;
        int l = l0 - 2 + r;
        unsigned int pk[4] = {0, 0, 0, 0};
        if (l >= 0 && l < L_) {
            const float* src = x + (((size_t)(n * L_ + l)) << 8) + (slot << 4);
            #pragma unroll
            for (int q = 0; q < 4; ++q) {
                f32x4 f = *reinterpret_cast<const f32x4*>(src + q * 4);
                pk[q] = (unsigned int)f2q(f[0]) | ((unsigned int)f2q(f[1]) << 8) |
                        ((unsigned int)f2q(f[2]) << 16) | ((unsigned int)f2q(f[3]) << 24);
            }
        }
        *reinterpret_cast<uint4*>(xt + r * 256 + ((slot ^ (r & 15)) << 4)) =
            make_uint4(pk[0], pk[1], pk[2], pk[3]);
    }
    __syncthreads();

    // ---- conv1: software-pipelined karm loop ----
    f32x4 acc1[3][2] = {};
    LDB(bpk1, 1, Bb);  CONV1K(0, Ba);
    LDB(bpk1, 2, Ba);  CONV1K(1, Bb);
    LDB(bpk2, 0, Bb);  CONV1K(2, Ba);
    LDB(bpk2, 1, Ba);                                // hides under epilogue

    // ---- conv1 stats: shfl over 16 cols x 2cg, LDS combine over 8 waves ----
    const float cb10 = b1[col0], cb11 = b1[col1];
    const float cg10 = g1[col0], cg11 = g1[col1];
    const float ce10 = be1[col0], ce11 = be1[col1];
    {
        float sv[12], qv[12];
        #pragma unroll
        for (int t = 0; t < 3; ++t)
            #pragma unroll
            for (int j = 0; j < 4; ++j) {
                float h0 = acc1[t][0][j] + cb10, h1 = acc1[t][1][j] + cb11;
                sv[t*4+j] = h0 + h1; qv[t*4+j] = h0 * h0 + h1 * h1;
            }
        #pragma unroll
        for (int m = 1; m < 16; m <<= 1)
            #pragma unroll
            for (int k = 0; k < 12; ++k) {
                sv[k] += __shfl_xor(sv[k], m, 64);
                qv[k] += __shfl_xor(qv[k], m, 64);
            }
        if (lr == 0) {
            #pragma unroll
            for (int t = 0; t < 3; ++t)
                #pragma unroll
                for (int j = 0; j < 4; ++j) {
                    redS[wv][16*t + lg*4 + j] = sv[t*4+j];
                    redQ[wv][16*t + lg*4 + j] = qv[t*4+j];
                }
        }
    }
    __syncthreads();
    if (tid < 48) {
        float ss = 0.f, qq = 0.f;
        #pragma unroll
        for (int u = 0; u < 8; ++u) { ss += redS[u][tid]; qq += redQ[u][tid]; }
        float m_  = ss * (1.f / 256.f);
        float var = fmaxf(qq * (1.f / 256.f) - m_ * m_, 0.f);
        redS[0][tid] = m_;
        redQ[0][tid] = 1.0f / sqrtf(var + EPSL);
    }
    __syncthreads();

    // ---- normalize + ReLU -> h1t fp8 (rows 0..33 kept) ----
    #pragma unroll
    for (int t = 0; t < 3; ++t)
        #pragma unroll
        for (int j = 0; j < 4; ++j) {
            int hr = 16*t + lg*4 + j;
            if (hr < 34) {
                int hl = l0 - 1 + hr;
                float r0 = 0.f, r1 = 0.f;
                if (hl >= 0 && hl < L_) {
                    r0 = fmaxf((acc1[t][0][j] + cb10 - redS[0][hr]) * redQ[0][hr] * cg10 + ce10, 0.f);
                    r1 = fmaxf((acc1[t][1][j] + cb11 - redS[0][hr]) * redQ[0][hr] * cg11 + ce11, 0.f);
                }
                *(unsigned char*)(h1t + hr*256 + (((col0 >> 4) ^ (hr & 15)) << 4) + (col0 & 15)) = f2q(r0);
                *(unsigned char*)(h1t + hr*256 + (((col1 >> 4) ^ (hr & 15)) << 4) + (col1 & 15)) = f2q(r1);
            }
        }
    __syncthreads();

    // ---- conv2: software-pipelined karm loop (Bb holds k0, Ba holds k1) ----
    f32x4 c2[2][2] = {};
    CONV2K(0, Bb);  LDB(bpk2, 2, Bb);
    CONV2K(1, Ba);
    CONV2K(2, Bb);

    // ---- conv2 stats ----
    const float cb20 = b2[col0], cb21 = b2[col1];
    const float cg20 = g2[col0], cg21 = g2[col1];
    const float ce20 = be2[col0], ce21 = be2[col1];
    const float lw0  = lw[col0],  lw1  = lw[col1];
    {
        float sv[8], qv[8];
        #pragma unroll
        for (int tt = 0; tt < 2; ++tt)
            #pragma unroll
            for (int j = 0; j < 4; ++j) {
                float h0 = c2[tt][0][j] + cb20, h1 = c2[tt][1][j] + cb21;
                sv[tt*4+j] = h0 + h1; qv[tt*4+j] = h0 * h0 + h1 * h1;
            }
        #pragma unroll
        for (int m = 1; m < 16; m <<= 1)
            #pragma unroll
            for (int k = 0; k < 8; ++k) {
                sv[k] += __shfl_xor(sv[k], m, 64);
                qv[k] += __shfl_xor(qv[k], m, 64);
            }
        if (lr == 0) {
            #pragma unroll
            for (int tt = 0; tt < 2; ++tt)
                #pragma unroll
                for (int j = 0; j < 4; ++j) {
                    redS[wv][16*tt + lg*4 + j] = sv[tt*4+j];
                    redQ[wv][16*tt + lg*4 + j] = qv[tt*4+j];
                }
        }
    }
    __syncthreads();
    if (tid < 32) {
        float ss = 0.f, qq = 0.f;
        #pragma unroll
        for (int u = 0; u < 8; ++u) { ss += redS[u][tid]; qq += redQ[u][tid]; }
        float m_  = ss * (1.f / 256.f);
        float var = fmaxf(qq * (1.f / 256.f) - m_ * m_, 0.f);
        redS[0][tid] = m_;
        redQ[0][tid] = 1.0f / sqrtf(var + EPSL);
    }
    __syncthreads();

    // ---- LN + ReLU + dot(lw) -> dur ----
    {
        float pv[8];
        #pragma unroll
        for (int tt = 0; tt < 2; ++tt)
            #pragma unroll
            for (int j = 0; j < 4; ++j) {
                int r = 16*tt + lg*4 + j;
                float r0 = fmaxf((c2[tt][0][j] + cb20 - redS[0][r]) * redQ[0][r] * cg20 + ce20, 0.f);
                float r1 = fmaxf((c2[tt][1][j] + cb21 - redS[0][r]) * redQ[0][r] * cg21 + ce21, 0.f);
                pv[tt*4+j] = r0 * lw0 + r1 * lw1;
            }
        #pragma unroll
        for (int m = 1; m < 16; m <<= 1)
            #pragma unroll
            for (int k = 0; k < 8; ++k)
                pv[k] += __shfl_xor(pv[k], m, 64);
        if (lr == 0) {
            #pragma unroll
            for (int tt = 0; tt < 2; ++tt)
                #pragma unroll
                for (int j = 0; j < 4; ++j)
                    redP[wv][16*tt + lg*4 + j] = pv[tt*4+j];
        }
    }
    __syncthreads();
    if (tid < 32) {
        float dot = lb[0];
        #pragma unroll
        for (int u = 0; u < 8; ++u) dot += redP[u][tid];
        dur[n * L_ + l0 + tid] = (int)(fmaxf(dot, 0.f) + 0.5f);
    }
}

// ---------------------------------------------------------------------------
// gather: inline per-block scan of dur (wave 0) -> LDS ends; 8 rows/block;
// binary search in LDS; nontemporal float4 stores.
// ---------------------------------------------------------------------------
__global__ __launch_bounds__(512) void gather_kernel(
    const float* __restrict__ x, const int* __restrict__ dur,
    float* __restrict__ out)
{
    __shared__ __align__(16) int se[L_];
    const int wid = threadIdx.x >> 6, lane = threadIdx.x & 63;
    const int blk = blockIdx.x;
    const int n = blk >> 9;                 // 512 blocks per batch row

    if (wid == 0) {
        const int* dsrc = dur + n * L_;
        int4 va = reinterpret_cast<const int4*>(dsrc)[lane * 2];
        int4 vb = reinterpret_cast<const int4*>(dsrc)[lane * 2 + 1];
        int p0 = va.x,      p1 = p0 + va.y, p2 = p1 + va.z, p3 = p2 + va.w;
        int p4 = p3 + vb.x, p5 = p4 + vb.y, p6 = p5 + vb.z, p7 = p6 + vb.w;
        int tot = p7;
        #pragma unroll
        for (int m = 1; m < 64; m <<= 1) {
            int tu = __shfl_up(tot, m, 64);
            if (lane >= m) tot += tu;
        }
        int off = tot - p7;
        reinterpret_cast<int4*>(se)[lane * 2]     = make_int4(p0+off, p1+off, p2+off, p3+off);
        reinterpret_cast<int4*>(se)[lane * 2 + 1] = make_int4(p4+off, p5+off, p6+off, p7+off);
    }
    __syncthreads();

    const int t = ((blk & 511) << 3) + wid;
    const int total = se[L_ - 1];

    f32x4 v = {0.f, 0.f, 0.f, 0.f};
    if (t < total) {
        int p = 0;
        #pragma unroll
        for (int step = 256; step > 0; step >>= 1)
            if (p + step <= L_ && se[p + step - 1] <= t) p += step;
        v = reinterpret_cast<const f32x4*>(x + (((size_t)(n * L_ + p)) << 8))[lane];
    }
    __builtin_nontemporal_store(
        v, reinterpret_cast<f32x4*>(out + (((size_t)(n * T_ + t)) << 8)) + lane);
}

// ---------------------------------------------------------------------------
extern "C" void kernel_launch(void* const* d_in, const int* in_sizes, int n_in,
                              void* d_out, int out_size, void* d_ws, size_t ws_size,
                              hipStream_t stream)
{
    const float* x   = (const float*)d_in[0];
    const float* w1  = (const float*)d_in[1];
    const float* b1  = (const float*)d_in[2];
    const float* g1  = (const float*)d_in[3];
    const float* be1 = (const float*)d_in[4];
    const float* w2  = (const float*)d_in[5];
    const float* b2  = (const float*)d_in[6];
    const float* g2  = (const float*)d_in[7];
    const float* be2 = (const float*)d_in[8];
    const float* lw  = (const float*)d_in[9];
    const float* lb  = (const float*)d_in[10];

    float* out = (float*)d_out;
    // fp8 weight-fragment scratch in d_out head (384 KB; gather overwrites)
    unsigned char* bpk1 = (unsigned char*)d_out;
    unsigned char* bpk2 = bpk1 + 196608;
    int* dur = (int*)d_ws;

    pack_w_kernel<<<192, 256, 0, stream>>>(w1, w2, bpk1, bpk2,
                                           out + (size_t)N_ * T_ * C_);

    fused_conv_kernel<<<N_ * (L_ / BM), 512, 0, stream>>>(
        x, bpk1, bpk2, b1, g1, be1, b2, g2, be2, lw, lb, dur);

    gather_kernel<<<N_ * T_ / 8, 512, 0, stream>>>(x, dur, out);
}